// Round 1
// baseline (906.226 us; speedup 1.0000x reference)
//
#include <hip/hip_runtime.h>

#define NEG_SLOPE 0.2f

// ---------------- graph preprocessing ----------------

__global__ void k_deg_ea(const int* __restrict__ tgt, const float* __restrict__ ea,
                         int* __restrict__ deg, float* __restrict__ ea_sum, int E) {
  int e = blockIdx.x * blockDim.x + threadIdx.x;
  if (e >= E) return;
  int t = tgt[e];
  float4 v = *reinterpret_cast<const float4*>(ea + (size_t)e * 4);
  atomicAdd(&deg[t], 1);
  atomicAdd(&ea_sum[t * 4 + 0], v.x);
  atomicAdd(&ea_sum[t * 4 + 1], v.y);
  atomicAdd(&ea_sum[t * 4 + 2], v.z);
  atomicAdd(&ea_sum[t * 4 + 3], v.w);
}

__global__ void k_loopattr(const int* __restrict__ deg, const float* __restrict__ ea_sum,
                           float* __restrict__ lattr, int N) {
  int n = blockIdx.x * blockDim.x + threadIdx.x;
  if (n >= N) return;
  float inv = 1.0f / (float)max(deg[n], 1);
  float4 s = *reinterpret_cast<const float4*>(ea_sum + (size_t)n * 4);
  *reinterpret_cast<float4*>(lattr + (size_t)n * 4) =
      make_float4(s.x * inv, s.y * inv, s.z * inv, s.w * inv);
}

// off[0] = 0; off[i+1] = sum_{j<=i} (deg[j]+1)   (single block, carry loop)
__global__ void k_scan(const int* __restrict__ deg, int* __restrict__ off, int n) {
  __shared__ int s[1024];
  __shared__ int carry;
  int tid = threadIdx.x;
  if (tid == 0) { carry = 0; off[0] = 0; }
  __syncthreads();
  for (int base = 0; base < n; base += 1024) {
    int i = base + tid;
    int v = (i < n) ? deg[i] + 1 : 0;
    s[tid] = v;
    __syncthreads();
    for (int o = 1; o < 1024; o <<= 1) {
      int t = (tid >= o) ? s[tid - o] : 0;
      __syncthreads();
      s[tid] += t;
      __syncthreads();
    }
    if (i < n) off[i + 1] = carry + s[tid];
    __syncthreads();
    if (tid == 0) carry += s[1023];
    __syncthreads();
  }
}

__global__ void k_fillself(const int* __restrict__ off, int2* __restrict__ csr, int E, int N) {
  int n = blockIdx.x * blockDim.x + threadIdx.x;
  if (n >= N) return;
  csr[off[n + 1] - 1] = make_int2(n, E + n);  // self-loop in the last slot
}

__global__ void k_filledge(const int* __restrict__ src, const int* __restrict__ tgt,
                           const int* __restrict__ off, int* __restrict__ cur,
                           int2* __restrict__ csr, int E) {
  int e = blockIdx.x * blockDim.x + threadIdx.x;
  if (e >= E) return;
  int t = tgt[e];
  int pos = off[t] + atomicAdd(&cur[t], 1);
  csr[pos] = make_int2(src[e], e);
}

// M[layer][k][h] = sum_c We[k,h*16+c] * ae[h*16+c]
__global__ void k_M(const float* __restrict__ We1, const float* __restrict__ ae1,
                    const float* __restrict__ We2, const float* __restrict__ ae2,
                    float* __restrict__ M) {
  int tid = threadIdx.x;
  if (tid >= 64) return;
  int layer = tid >> 5, kh = tid & 31;
  int k = kh >> 3, h = kh & 7;
  const float* We = layer ? We2 : We1;
  const float* ae = layer ? ae2 : ae1;
  float acc = 0.f;
  for (int c = 0; c < 16; ++c) acc += We[k * 128 + h * 16 + c] * ae[h * 16 + c];
  M[layer * 32 + k * 8 + h] = acc;
}

// ---------------- layer kernels ----------------

// h = x @ W1 (x is [N,4]); a_s[n,h] = sum_c h*as ; a_d similarly
__global__ __launch_bounds__(256) void k_node1(const float* __restrict__ x,
    const float* __restrict__ W, const float* __restrict__ as_, const float* __restrict__ ad_,
    float* __restrict__ h, float* __restrict__ a_s, float* __restrict__ a_d, int N) {
  __shared__ float Wl[512];
  __shared__ float asl[128], adl[128];
  int tid = threadIdx.x;
  for (int i = tid; i < 512; i += 256) Wl[i] = W[i];
  if (tid < 128) { asl[tid] = as_[tid]; adl[tid] = ad_[tid]; }
  __syncthreads();
  int c = tid & 127, half = tid >> 7;
  for (int n0 = blockIdx.x * 2; n0 < N; n0 += gridDim.x * 2) {
    int n = n0 + half;
    if (n < N) {
      float4 xr = *reinterpret_cast<const float4*>(x + (size_t)n * 4);
      float hv = xr.x * Wl[c] + xr.y * Wl[128 + c] + xr.z * Wl[256 + c] + xr.w * Wl[384 + c];
      h[(size_t)n * 128 + c] = hv;
      float ps = hv * asl[c], pd = hv * adl[c];
      for (int o = 1; o < 16; o <<= 1) { ps += __shfl_xor(ps, o, 64); pd += __shfl_xor(pd, o, 64); }
      if ((c & 15) == 0) { a_s[n * 8 + (c >> 4)] = ps; a_d[n * 8 + (c >> 4)] = pd; }
    }
  }
}

// h = x @ W2 (x is [N,128], W2 staged in LDS); same epilogue
__global__ __launch_bounds__(256) void k_node2(const float* __restrict__ x,
    const float* __restrict__ W, const float* __restrict__ as_, const float* __restrict__ ad_,
    float* __restrict__ h, float* __restrict__ a_s, float* __restrict__ a_d, int N) {
  __shared__ float Wl[128 * 128];
  __shared__ float xl[256];
  __shared__ float asl[128], adl[128];
  int tid = threadIdx.x;
  for (int i = tid; i < 16384; i += 256) Wl[i] = W[i];
  if (tid < 128) { asl[tid] = as_[tid]; adl[tid] = ad_[tid]; }
  __syncthreads();
  int c = tid & 127, half = tid >> 7;
  for (int n0 = blockIdx.x * 2; n0 < N; n0 += gridDim.x * 2) {
    int nn = n0 + half;
    __syncthreads();
    if (nn < N) xl[tid] = x[(size_t)nn * 128 + c];
    __syncthreads();
    if (nn < N) {
      const float* xr = &xl[half * 128];
      float hv = 0.f;
      #pragma unroll 8
      for (int k = 0; k < 128; ++k) hv += xr[k] * Wl[k * 128 + c];
      h[(size_t)nn * 128 + c] = hv;
      float ps = hv * asl[c], pd = hv * adl[c];
      for (int o = 1; o < 16; o <<= 1) { ps += __shfl_xor(ps, o, 64); pd += __shfl_xor(pd, o, 64); }
      if ((c & 15) == 0) { a_s[nn * 8 + (c >> 4)] = ps; a_d[nn * 8 + (c >> 4)] = pd; }
    }
  }
}

// alpha[e,h] = leaky_relu(a_s[src]+a_d[tgt]+ea.M)
__global__ void k_edge(const int* __restrict__ src, const int* __restrict__ tgt,
    const float* __restrict__ eattr, const float* __restrict__ lattr,
    const float* __restrict__ a_s, const float* __restrict__ a_d,
    const float* __restrict__ M, float* __restrict__ alpha, int E, int E2) {
  int e = blockIdx.x * blockDim.x + threadIdx.x;
  if (e >= E2) return;
  int s, t; float4 ea;
  if (e < E) {
    s = src[e]; t = tgt[e];
    ea = *reinterpret_cast<const float4*>(eattr + (size_t)e * 4);
  } else {
    s = t = e - E;
    ea = *reinterpret_cast<const float4*>(lattr + (size_t)(e - E) * 4);
  }
  float4 s0 = *reinterpret_cast<const float4*>(a_s + (size_t)s * 8);
  float4 s1 = *reinterpret_cast<const float4*>(a_s + (size_t)s * 8 + 4);
  float4 d0 = *reinterpret_cast<const float4*>(a_d + (size_t)t * 8);
  float4 d1 = *reinterpret_cast<const float4*>(a_d + (size_t)t * 8 + 4);
  float sv[8] = {s0.x, s0.y, s0.z, s0.w, s1.x, s1.y, s1.z, s1.w};
  float dv[8] = {d0.x, d0.y, d0.z, d0.w, d1.x, d1.y, d1.z, d1.w};
  float o[8];
  #pragma unroll
  for (int h = 0; h < 8; ++h) {
    float aeh = ea.x * M[h] + ea.y * M[8 + h] + ea.z * M[16 + h] + ea.w * M[24 + h];
    float a = sv[h] + dv[h] + aeh;
    o[h] = a > 0.f ? a : NEG_SLOPE * a;
  }
  *reinterpret_cast<float4*>(alpha + (size_t)e * 8)     = make_float4(o[0], o[1], o[2], o[3]);
  *reinterpret_cast<float4*>(alpha + (size_t)e * 8 + 4) = make_float4(o[4], o[5], o[6], o[7]);
}

// one wave per target node: softmax-weighted aggregate, + bias, relu
__global__ __launch_bounds__(256) void k_aggr(const int2* __restrict__ csr,
    const int* __restrict__ off, const float* __restrict__ alpha,
    const float* __restrict__ h, const float* __restrict__ bias,
    float* __restrict__ xout, int N) {
  int wid = (blockIdx.x * blockDim.x + threadIdx.x) >> 6;
  if (wid >= N) return;
  int lane = threadIdx.x & 63;
  int head = lane >> 3;                 // channels (2*lane, 2*lane+1) are in head lane>>3
  int beg = off[wid], end = off[wid + 1];
  float m = -1e30f;
  for (int i = beg; i < end; ++i) {
    int eid = csr[i].y;
    m = fmaxf(m, alpha[(size_t)eid * 8 + head]);
  }
  float sum = 0.f, acc0 = 0.f, acc1 = 0.f;
  for (int i = beg; i < end; ++i) {
    int2 ce = csr[i];
    float a = alpha[(size_t)ce.y * 8 + head];
    float ex = __expf(a - m);
    sum += ex;
    float2 hv = *reinterpret_cast<const float2*>(h + (size_t)ce.x * 128 + lane * 2);
    acc0 += ex * hv.x;
    acc1 += ex * hv.y;
  }
  float inv = 1.f / (sum + 1e-16f);
  float o0 = fmaxf(acc0 * inv + bias[lane * 2], 0.f);
  float o1 = fmaxf(acc1 * inv + bias[lane * 2 + 1], 0.f);
  *reinterpret_cast<float2*>(xout + (size_t)wid * 128 + lane * 2) = make_float2(o0, o1);
}

// ---------------- pooling + FC ----------------

__global__ void k_pool(const float* __restrict__ x, const int* __restrict__ batch,
                       float* __restrict__ pool, int* __restrict__ cntg, int N) {
  int idx = blockIdx.x * blockDim.x + threadIdx.x;
  int n = idx >> 7, c = idx & 127;
  if (n >= N) return;
  int g = batch[n];
  atomicAdd(&pool[(size_t)g * 128 + c], x[(size_t)n * 128 + c]);
  if (c == 0) atomicAdd(&cntg[g], 1);
}

__global__ __launch_bounds__(128) void k_fc(const float* __restrict__ pool,
    const int* __restrict__ cntg, const float* __restrict__ fcw,
    const float* __restrict__ fcb, float* __restrict__ out, int G) {
  int g = blockIdx.x, c = threadIdx.x;
  __shared__ float r0[2], r1[2];
  float inv = 1.f / (float)max(cntg[g], 1);
  float v = pool[(size_t)g * 128 + c] * inv;
  float p0 = v * fcw[c * 2], p1 = v * fcw[c * 2 + 1];
  for (int o = 1; o < 64; o <<= 1) { p0 += __shfl_xor(p0, o, 64); p1 += __shfl_xor(p1, o, 64); }
  if ((c & 63) == 0) { r0[c >> 6] = p0; r1[c >> 6] = p1; }
  __syncthreads();
  if (c == 0) {
    out[g * 2]     = r0[0] + r0[1] + fcb[0];
    out[g * 2 + 1] = r1[0] + r1[1] + fcb[1];
  }
}

// ---------------- host ----------------

extern "C" void kernel_launch(void* const* d_in, const int* in_sizes, int n_in,
                              void* d_out, int out_size, void* d_ws, size_t ws_size,
                              hipStream_t stream) {
  const float* x     = (const float*)d_in[0];
  const int*   eidx  = (const int*)d_in[1];
  const int*   batch = (const int*)d_in[2];
  const float* eattr = (const float*)d_in[3];
  const float* W1  = (const float*)d_in[4];
  const float* as1 = (const float*)d_in[5];
  const float* ad1 = (const float*)d_in[6];
  const float* We1 = (const float*)d_in[7];
  const float* ae1 = (const float*)d_in[8];
  const float* b1  = (const float*)d_in[9];
  const float* W2  = (const float*)d_in[10];
  const float* as2 = (const float*)d_in[11];
  const float* ad2 = (const float*)d_in[12];
  const float* We2 = (const float*)d_in[13];
  const float* ae2 = (const float*)d_in[14];
  const float* b2  = (const float*)d_in[15];
  const float* fcw = (const float*)d_in[16];
  const float* fcb = (const float*)d_in[17];

  const int N  = in_sizes[2];
  const int E  = in_sizes[1] / 2;
  const int G  = out_size / 2;
  const int E2 = E + N;
  const int* srcI = eidx;
  const int* tgtI = eidx + E;

  char* w = (char*)d_ws;
  auto alloc = [&](size_t bytes) -> void* {
    void* p = (void*)w;
    w += (bytes + 255) & ~(size_t)255;
    return p;
  };
  int*   deg    = (int*)alloc((size_t)N * 4);
  int*   cur    = (int*)alloc((size_t)N * 4);
  int*   off    = (int*)alloc((size_t)(N + 1) * 4);
  float* ea_sum = (float*)alloc((size_t)N * 16);
  float* lattr  = (float*)alloc((size_t)N * 16);
  int2*  csr    = (int2*)alloc((size_t)E2 * 8);
  float* a_s    = (float*)alloc((size_t)N * 32);
  float* a_d    = (float*)alloc((size_t)N * 32);
  float* alpha  = (float*)alloc((size_t)E2 * 32);
  float* hbuf   = (float*)alloc((size_t)N * 512);
  float* xbuf   = (float*)alloc((size_t)N * 512);
  float* M      = (float*)alloc(256);
  float* pool   = (float*)alloc((size_t)G * 512);
  int*   cntg   = (int*)alloc((size_t)G * 4);

  hipMemsetAsync(deg, 0, (size_t)N * 4, stream);
  hipMemsetAsync(cur, 0, (size_t)N * 4, stream);
  hipMemsetAsync(ea_sum, 0, (size_t)N * 16, stream);
  hipMemsetAsync(pool, 0, (size_t)G * 512, stream);
  hipMemsetAsync(cntg, 0, (size_t)G * 4, stream);

  k_deg_ea<<<(E + 255) / 256, 256, 0, stream>>>(tgtI, eattr, deg, ea_sum, E);
  k_loopattr<<<(N + 255) / 256, 256, 0, stream>>>(deg, ea_sum, lattr, N);
  k_scan<<<1, 1024, 0, stream>>>(deg, off, N);
  k_fillself<<<(N + 255) / 256, 256, 0, stream>>>(off, csr, E, N);
  k_filledge<<<(E + 255) / 256, 256, 0, stream>>>(srcI, tgtI, off, cur, csr, E);
  k_M<<<1, 64, 0, stream>>>(We1, ae1, We2, ae2, M);

  // layer 1
  k_node1<<<(N + 1) / 2, 256, 0, stream>>>(x, W1, as1, ad1, hbuf, a_s, a_d, N);
  k_edge<<<(E2 + 255) / 256, 256, 0, stream>>>(srcI, tgtI, eattr, lattr, a_s, a_d, M, alpha, E, E2);
  k_aggr<<<(N + 3) / 4, 256, 0, stream>>>(csr, off, alpha, hbuf, b1, xbuf, N);

  // layer 2
  k_node2<<<512, 256, 0, stream>>>(xbuf, W2, as2, ad2, hbuf, a_s, a_d, N);
  k_edge<<<(E2 + 255) / 256, 256, 0, stream>>>(srcI, tgtI, eattr, lattr, a_s, a_d, M + 32, alpha, E, E2);
  k_aggr<<<(N + 3) / 4, 256, 0, stream>>>(csr, off, alpha, hbuf, b2, xbuf, N);

  // pool + fc
  k_pool<<<(int)(((size_t)N * 128 + 255) / 256), 256, 0, stream>>>(xbuf, batch, pool, cntg, N);
  k_fc<<<G, 128, 0, stream>>>(pool, cntg, fcw, fcb, (float*)d_out, G);
}

// Round 2
// 522.811 us; speedup vs baseline: 1.7334x; 1.7334x over previous
//
#include <hip/hip_runtime.h>

#define NEG_SLOPE 0.2f

// ---------------- graph preprocessing ----------------

__global__ void k_deg(const int* __restrict__ tgt, int* __restrict__ deg, int E) {
  int e = blockIdx.x * blockDim.x + threadIdx.x;
  if (e < E) atomicAdd(&deg[tgt[e]], 1);
}

// off[0]=0; off[i+1]=sum_{j<=i}(deg[j]+1). Single block, wave-shuffle scan.
__global__ __launch_bounds__(1024) void k_scan(const int* __restrict__ deg,
                                               int* __restrict__ off, int n) {
  __shared__ int wsum[16];
  __shared__ int carry_s;
  int tid = threadIdx.x, lane = tid & 63, wv = tid >> 6;
  if (tid == 0) { carry_s = 0; off[0] = 0; }
  __syncthreads();
  for (int base = 0; base < n; base += 4096) {
    int i0 = base + tid * 4;
    int v[4];
    #pragma unroll
    for (int j = 0; j < 4; ++j) { int i = i0 + j; v[j] = (i < n) ? deg[i] + 1 : 0; }
    v[1] += v[0]; v[2] += v[1]; v[3] += v[2];
    int tsum = v[3];
    int sc = tsum;
    #pragma unroll
    for (int o = 1; o < 64; o <<= 1) { int t = __shfl_up(sc, o, 64); if (lane >= o) sc += t; }
    if (lane == 63) wsum[wv] = sc;
    __syncthreads();
    if (wv == 0 && lane < 16) {
      int ws = wsum[lane];
      #pragma unroll
      for (int o = 1; o < 16; o <<= 1) { int t = __shfl_up(ws, o, 64); if (lane >= o) ws += t; }
      wsum[lane] = ws;
    }
    __syncthreads();
    int excl = carry_s + (wv ? wsum[wv - 1] : 0) + sc - tsum;
    #pragma unroll
    for (int j = 0; j < 4; ++j) { int i = i0 + j; if (i < n) off[i + 1] = excl + v[j]; }
    __syncthreads();
    if (tid == 0) carry_s += wsum[15];
    __syncthreads();
  }
}

__global__ void k_fillself(const int* __restrict__ off, int2* __restrict__ csr, int E, int N) {
  int n = blockIdx.x * blockDim.x + threadIdx.x;
  if (n >= N) return;
  csr[off[n + 1] - 1] = make_int2(n, E + n);  // self-loop in the last slot
}

__global__ void k_filledge(const int* __restrict__ src, const int* __restrict__ tgt,
                           const int* __restrict__ off, int* __restrict__ cur,
                           int2* __restrict__ csr, int E) {
  int e = blockIdx.x * blockDim.x + threadIdx.x;
  if (e >= E) return;
  int t = tgt[e];
  int pos = off[t] + atomicAdd(&cur[t], 1);
  csr[pos] = make_int2(src[e], e);
}

// loop_attr[n] = mean of incoming eattr rows (0 if none) — from CSR, no atomics
__global__ void k_loopattr(const int2* __restrict__ csr, const int* __restrict__ off,
                           const float* __restrict__ eattr, float* __restrict__ lattr, int N) {
  int idx = blockIdx.x * blockDim.x + threadIdx.x;
  int n = idx >> 2, c = idx & 3;
  if (n >= N) return;
  int beg = off[n], end = off[n + 1] - 1;  // exclude self slot
  float s = 0.f;
  for (int i = beg; i < end; ++i) s += eattr[(size_t)csr[i].y * 4 + c];
  lattr[n * 4 + c] = s / (float)max(end - beg, 1);
}

// M[layer][k][h] = sum_c We[k,h*16+c] * ae[h*16+c]
__global__ void k_M(const float* __restrict__ We1, const float* __restrict__ ae1,
                    const float* __restrict__ We2, const float* __restrict__ ae2,
                    float* __restrict__ M) {
  int tid = threadIdx.x;
  if (tid >= 64) return;
  int layer = tid >> 5, kh = tid & 31;
  int k = kh >> 3, h = kh & 7;
  const float* We = layer ? We2 : We1;
  const float* ae = layer ? ae2 : ae1;
  float acc = 0.f;
  for (int c = 0; c < 16; ++c) acc += We[k * 128 + h * 16 + c] * ae[h * 16 + c];
  M[layer * 32 + k * 8 + h] = acc;
}

// ---------------- layer kernels ----------------

__global__ __launch_bounds__(256) void k_node1(const float* __restrict__ x,
    const float* __restrict__ W, const float* __restrict__ as_, const float* __restrict__ ad_,
    float* __restrict__ h, float* __restrict__ a_s, float* __restrict__ a_d, int N) {
  __shared__ float Wl[512];
  __shared__ float asl[128], adl[128];
  int tid = threadIdx.x;
  for (int i = tid; i < 512; i += 256) Wl[i] = W[i];
  if (tid < 128) { asl[tid] = as_[tid]; adl[tid] = ad_[tid]; }
  __syncthreads();
  int c = tid & 127, half = tid >> 7;
  for (int n0 = blockIdx.x * 2; n0 < N; n0 += gridDim.x * 2) {
    int n = n0 + half;
    if (n < N) {
      float4 xr = *reinterpret_cast<const float4*>(x + (size_t)n * 4);
      float hv = xr.x * Wl[c] + xr.y * Wl[128 + c] + xr.z * Wl[256 + c] + xr.w * Wl[384 + c];
      h[(size_t)n * 128 + c] = hv;
      float ps = hv * asl[c], pd = hv * adl[c];
      for (int o = 1; o < 16; o <<= 1) { ps += __shfl_xor(ps, o, 64); pd += __shfl_xor(pd, o, 64); }
      if ((c & 15) == 0) { a_s[n * 8 + (c >> 4)] = ps; a_d[n * 8 + (c >> 4)] = pd; }
    }
  }
}

// h = x @ W2, float4 register tile: thread = (node, 4 channels)
__global__ __launch_bounds__(256) void k_node2(const float* __restrict__ x,
    const float* __restrict__ W, const float* __restrict__ as_, const float* __restrict__ ad_,
    float* __restrict__ h, float* __restrict__ a_s, float* __restrict__ a_d, int N) {
  __shared__ float4 Wl[128 * 32];     // Wl[k*32+cg] = W[k][cg*4..cg*4+3]  (64 KiB)
  __shared__ float xl[8][128];
  __shared__ float asl[128], adl[128];
  int tid = threadIdx.x;
  for (int i = tid; i < 4096; i += 256) Wl[i] = reinterpret_cast<const float4*>(W)[i];
  if (tid < 128) { asl[tid] = as_[tid]; adl[tid] = ad_[tid]; }
  __syncthreads();
  int node = tid >> 5, cg = tid & 31;
  for (int n0 = blockIdx.x * 8; n0 < N; n0 += gridDim.x * 8) {
    __syncthreads();
    #pragma unroll
    for (int j = 0; j < 4; ++j) {
      int idx = tid + j * 256;
      int r = idx >> 7, cc = idx & 127;
      int nn = n0 + r;
      xl[r][cc] = (nn < N) ? x[(size_t)nn * 128 + cc] : 0.f;
    }
    __syncthreads();
    int nn = n0 + node;
    float4 acc = make_float4(0.f, 0.f, 0.f, 0.f);
    #pragma unroll 4
    for (int k = 0; k < 128; ++k) {
      float xv = xl[node][k];
      float4 wv = Wl[k * 32 + cg];
      acc.x += xv * wv.x; acc.y += xv * wv.y; acc.z += xv * wv.z; acc.w += xv * wv.w;
    }
    if (nn < N) {
      *reinterpret_cast<float4*>(h + (size_t)nn * 128 + cg * 4) = acc;
      float ps = acc.x * asl[cg * 4] + acc.y * asl[cg * 4 + 1] +
                 acc.z * asl[cg * 4 + 2] + acc.w * asl[cg * 4 + 3];
      float pd = acc.x * adl[cg * 4] + acc.y * adl[cg * 4 + 1] +
                 acc.z * adl[cg * 4 + 2] + acc.w * adl[cg * 4 + 3];
      ps += __shfl_xor(ps, 1, 64); ps += __shfl_xor(ps, 2, 64);
      pd += __shfl_xor(pd, 1, 64); pd += __shfl_xor(pd, 2, 64);
      if ((cg & 3) == 0) { a_s[nn * 8 + (cg >> 2)] = ps; a_d[nn * 8 + (cg >> 2)] = pd; }
    }
  }
}

// alpha[e,h] = leaky_relu(a_s[src]+a_d[tgt]+ea.M)
__global__ void k_edge(const int* __restrict__ src, const int* __restrict__ tgt,
    const float* __restrict__ eattr, const float* __restrict__ lattr,
    const float* __restrict__ a_s, const float* __restrict__ a_d,
    const float* __restrict__ M, float* __restrict__ alpha, int E, int E2) {
  int e = blockIdx.x * blockDim.x + threadIdx.x;
  if (e >= E2) return;
  int s, t; float4 ea;
  if (e < E) {
    s = src[e]; t = tgt[e];
    ea = *reinterpret_cast<const float4*>(eattr + (size_t)e * 4);
  } else {
    s = t = e - E;
    ea = *reinterpret_cast<const float4*>(lattr + (size_t)(e - E) * 4);
  }
  float4 s0 = *reinterpret_cast<const float4*>(a_s + (size_t)s * 8);
  float4 s1 = *reinterpret_cast<const float4*>(a_s + (size_t)s * 8 + 4);
  float4 d0 = *reinterpret_cast<const float4*>(a_d + (size_t)t * 8);
  float4 d1 = *reinterpret_cast<const float4*>(a_d + (size_t)t * 8 + 4);
  float sv[8] = {s0.x, s0.y, s0.z, s0.w, s1.x, s1.y, s1.z, s1.w};
  float dv[8] = {d0.x, d0.y, d0.z, d0.w, d1.x, d1.y, d1.z, d1.w};
  float o[8];
  #pragma unroll
  for (int h = 0; h < 8; ++h) {
    float aeh = ea.x * M[h] + ea.y * M[8 + h] + ea.z * M[16 + h] + ea.w * M[24 + h];
    float a = sv[h] + dv[h] + aeh;
    o[h] = a > 0.f ? a : NEG_SLOPE * a;
  }
  *reinterpret_cast<float4*>(alpha + (size_t)e * 8)     = make_float4(o[0], o[1], o[2], o[3]);
  *reinterpret_cast<float4*>(alpha + (size_t)e * 8 + 4) = make_float4(o[4], o[5], o[6], o[7]);
}

// one wave per target node: ONLINE softmax aggregate (single CSR pass), + bias, relu
__global__ __launch_bounds__(256) void k_aggr(const int2* __restrict__ csr,
    const int* __restrict__ off, const float* __restrict__ alpha,
    const float* __restrict__ h, const float* __restrict__ bias,
    float* __restrict__ xout, int N) {
  int wid = (blockIdx.x * blockDim.x + threadIdx.x) >> 6;
  if (wid >= N) return;
  int lane = threadIdx.x & 63;
  int head = lane >> 3;
  int beg = off[wid], end = off[wid + 1];
  float m = -1e30f, sum = 0.f, acc0 = 0.f, acc1 = 0.f;
  for (int i = beg; i < end; ++i) {
    int2 ce = csr[i];
    float a = alpha[(size_t)ce.y * 8 + head];
    float2 hv = *reinterpret_cast<const float2*>(h + (size_t)ce.x * 128 + lane * 2);
    float nm = fmaxf(m, a);
    float r = __expf(m - nm);       // ==1 when max unchanged
    float ex = __expf(a - nm);
    sum = sum * r + ex;
    acc0 = acc0 * r + ex * hv.x;
    acc1 = acc1 * r + ex * hv.y;
    m = nm;
  }
  float inv = 1.f / (sum + 1e-16f);
  float o0 = fmaxf(acc0 * inv + bias[lane * 2], 0.f);
  float o1 = fmaxf(acc1 * inv + bias[lane * 2 + 1], 0.f);
  *reinterpret_cast<float2*>(xout + (size_t)wid * 128 + lane * 2) = make_float2(o0, o1);
}

// ---------------- pooling + FC ----------------

// batch is sorted: per-block register accumulate, flush atomics at boundaries
#define PROWS 128
__global__ __launch_bounds__(128) void k_pool(const float* __restrict__ x,
    const int* __restrict__ batch, float* __restrict__ pool, int* __restrict__ cntg, int N) {
  int c = threadIdx.x;
  int n0 = blockIdx.x * PROWS;
  if (n0 >= N) return;
  int nend = min(n0 + PROWS, N);
  float acc = 0.f; int cnt = 0; int g = batch[n0];
  for (int n = n0; n < nend; ++n) {
    int bn = batch[n];
    if (bn != g) {
      atomicAdd(&pool[(size_t)g * 128 + c], acc);
      if (c == 0) atomicAdd(&cntg[g], cnt);
      acc = 0.f; cnt = 0; g = bn;
    }
    acc += x[(size_t)n * 128 + c];
    cnt++;
  }
  atomicAdd(&pool[(size_t)g * 128 + c], acc);
  if (c == 0) atomicAdd(&cntg[g], cnt);
}

__global__ __launch_bounds__(128) void k_fc(const float* __restrict__ pool,
    const int* __restrict__ cntg, const float* __restrict__ fcw,
    const float* __restrict__ fcb, float* __restrict__ out, int G) {
  int g = blockIdx.x, c = threadIdx.x;
  __shared__ float r0[2], r1[2];
  float inv = 1.f / (float)max(cntg[g], 1);
  float v = pool[(size_t)g * 128 + c] * inv;
  float p0 = v * fcw[c * 2], p1 = v * fcw[c * 2 + 1];
  for (int o = 1; o < 64; o <<= 1) { p0 += __shfl_xor(p0, o, 64); p1 += __shfl_xor(p1, o, 64); }
  if ((c & 63) == 0) { r0[c >> 6] = p0; r1[c >> 6] = p1; }
  __syncthreads();
  if (c == 0) {
    out[g * 2]     = r0[0] + r0[1] + fcb[0];
    out[g * 2 + 1] = r1[0] + r1[1] + fcb[1];
  }
}

// ---------------- host ----------------

extern "C" void kernel_launch(void* const* d_in, const int* in_sizes, int n_in,
                              void* d_out, int out_size, void* d_ws, size_t ws_size,
                              hipStream_t stream) {
  const float* x     = (const float*)d_in[0];
  const int*   eidx  = (const int*)d_in[1];
  const int*   batch = (const int*)d_in[2];
  const float* eattr = (const float*)d_in[3];
  const float* W1  = (const float*)d_in[4];
  const float* as1 = (const float*)d_in[5];
  const float* ad1 = (const float*)d_in[6];
  const float* We1 = (const float*)d_in[7];
  const float* ae1 = (const float*)d_in[8];
  const float* b1  = (const float*)d_in[9];
  const float* W2  = (const float*)d_in[10];
  const float* as2 = (const float*)d_in[11];
  const float* ad2 = (const float*)d_in[12];
  const float* We2 = (const float*)d_in[13];
  const float* ae2 = (const float*)d_in[14];
  const float* b2  = (const float*)d_in[15];
  const float* fcw = (const float*)d_in[16];
  const float* fcb = (const float*)d_in[17];

  const int N  = in_sizes[2];
  const int E  = in_sizes[1] / 2;
  const int G  = out_size / 2;
  const int E2 = E + N;
  const int* srcI = eidx;
  const int* tgtI = eidx + E;

  char* w = (char*)d_ws;
  auto alloc = [&](size_t bytes) -> void* {
    void* p = (void*)w;
    w += (bytes + 255) & ~(size_t)255;
    return p;
  };
  int*   deg    = (int*)alloc((size_t)N * 8);        // deg + cur contiguous
  int*   cur    = deg + N;
  int*   off    = (int*)alloc((size_t)(N + 1) * 4);
  float* lattr  = (float*)alloc((size_t)N * 16);
  int2*  csr    = (int2*)alloc((size_t)E2 * 8);
  float* a_s    = (float*)alloc((size_t)N * 32);
  float* a_d    = (float*)alloc((size_t)N * 32);
  float* alpha  = (float*)alloc((size_t)E2 * 32);
  float* hbuf   = (float*)alloc((size_t)N * 512);
  float* xbuf   = (float*)alloc((size_t)N * 512);
  float* M      = (float*)alloc(256);
  float* pool   = (float*)alloc((size_t)G * 512 + (size_t)G * 4);  // pool + cntg contiguous
  int*   cntg   = (int*)(pool + (size_t)G * 128);

  hipMemsetAsync(deg, 0, (size_t)N * 8, stream);
  hipMemsetAsync(pool, 0, (size_t)G * 516, stream);

  k_deg<<<(E + 255) / 256, 256, 0, stream>>>(tgtI, deg, E);
  k_scan<<<1, 1024, 0, stream>>>(deg, off, N);
  k_fillself<<<(N + 255) / 256, 256, 0, stream>>>(off, csr, E, N);
  k_filledge<<<(E + 255) / 256, 256, 0, stream>>>(srcI, tgtI, off, cur, csr, E);
  k_loopattr<<<(N * 4 + 255) / 256, 256, 0, stream>>>(csr, off, eattr, lattr, N);
  k_M<<<1, 64, 0, stream>>>(We1, ae1, We2, ae2, M);

  // layer 1
  k_node1<<<(N + 1) / 2, 256, 0, stream>>>(x, W1, as1, ad1, hbuf, a_s, a_d, N);
  k_edge<<<(E2 + 255) / 256, 256, 0, stream>>>(srcI, tgtI, eattr, lattr, a_s, a_d, M, alpha, E, E2);
  k_aggr<<<(N + 3) / 4, 256, 0, stream>>>(csr, off, alpha, hbuf, b1, xbuf, N);

  // layer 2
  k_node2<<<1024, 256, 0, stream>>>(xbuf, W2, as2, ad2, hbuf, a_s, a_d, N);
  k_edge<<<(E2 + 255) / 256, 256, 0, stream>>>(srcI, tgtI, eattr, lattr, a_s, a_d, M + 32, alpha, E, E2);
  k_aggr<<<(N + 3) / 4, 256, 0, stream>>>(csr, off, alpha, hbuf, b2, xbuf, N);

  // pool + fc
  k_pool<<<(N + PROWS - 1) / PROWS, 128, 0, stream>>>(xbuf, batch, pool, cntg, N);
  k_fc<<<G, 128, 0, stream>>>(pool, cntg, fcw, fcb, (float*)d_out, G);
}

// Round 3
// 432.600 us; speedup vs baseline: 2.0948x; 1.2085x over previous
//
#include <hip/hip_runtime.h>

#define NEG_SLOPE 0.2f

// ---------------- graph preprocessing ----------------

__global__ void k_deg(const int* __restrict__ tgt, int* __restrict__ deg, int E) {
  int e = blockIdx.x * blockDim.x + threadIdx.x;
  if (e < E) atomicAdd(&deg[tgt[e]], 1);
}

// off[0]=0; off[i+1]=sum_{j<=i}(deg[j]+1). Single block, wave-shuffle scan.
__global__ __launch_bounds__(1024) void k_scan(const int* __restrict__ deg,
                                               int* __restrict__ off, int n) {
  __shared__ int wsum[16];
  __shared__ int carry_s;
  int tid = threadIdx.x, lane = tid & 63, wv = tid >> 6;
  if (tid == 0) { carry_s = 0; off[0] = 0; }
  __syncthreads();
  for (int base = 0; base < n; base += 4096) {
    int i0 = base + tid * 4;
    int v[4];
    #pragma unroll
    for (int j = 0; j < 4; ++j) { int i = i0 + j; v[j] = (i < n) ? deg[i] + 1 : 0; }
    v[1] += v[0]; v[2] += v[1]; v[3] += v[2];
    int tsum = v[3];
    int sc = tsum;
    #pragma unroll
    for (int o = 1; o < 64; o <<= 1) { int t = __shfl_up(sc, o, 64); if (lane >= o) sc += t; }
    if (lane == 63) wsum[wv] = sc;
    __syncthreads();
    if (wv == 0 && lane < 16) {
      int ws = wsum[lane];
      #pragma unroll
      for (int o = 1; o < 16; o <<= 1) { int t = __shfl_up(ws, o, 64); if (lane >= o) ws += t; }
      wsum[lane] = ws;
    }
    __syncthreads();
    int excl = carry_s + (wv ? wsum[wv - 1] : 0) + sc - tsum;
    #pragma unroll
    for (int j = 0; j < 4; ++j) { int i = i0 + j; if (i < n) off[i + 1] = excl + v[j]; }
    __syncthreads();
    if (tid == 0) carry_s += wsum[15];
    __syncthreads();
  }
}

__global__ void k_fillself(const int* __restrict__ off, int* __restrict__ csrc,
                           int* __restrict__ ceid, int E, int N) {
  int n = blockIdx.x * blockDim.x + threadIdx.x;
  if (n >= N) return;
  int p = off[n + 1] - 1;       // self-loop in the last slot
  csrc[p] = n;
  ceid[p] = E + n;
}

__global__ void k_filledge(const int* __restrict__ src, const int* __restrict__ tgt,
                           const int* __restrict__ off, int* __restrict__ cur,
                           int* __restrict__ csrc, int* __restrict__ ceid, int E) {
  int e = blockIdx.x * blockDim.x + threadIdx.x;
  if (e >= E) return;
  int t = tgt[e];
  int pos = off[t] + atomicAdd(&cur[t], 1);
  csrc[pos] = src[e];
  ceid[pos] = e;
}

// eaP[i] = eattr[eid] for regular CSR slots (self slots filled by k_loopattr)
__global__ void k_permute(const int* __restrict__ ceid, const float* __restrict__ eattr,
                          float4* __restrict__ eaP, int E, int E2) {
  int i = blockIdx.x * blockDim.x + threadIdx.x;
  if (i >= E2) return;
  int eid = ceid[i];
  if (eid < E) eaP[i] = reinterpret_cast<const float4*>(eattr)[eid];
}

// self-slot attr = mean of the node's incoming eaP rows (0 if none)
__global__ void k_loopattr(const int* __restrict__ off, float* __restrict__ eaP, int N) {
  int idx = blockIdx.x * blockDim.x + threadIdx.x;
  int n = idx >> 2, c = idx & 3;
  if (n >= N) return;
  int beg = off[n], end = off[n + 1] - 1;  // exclude self slot
  float s = 0.f;
  for (int i = beg; i < end; ++i) s += eaP[(size_t)i * 4 + c];
  eaP[(size_t)end * 4 + c] = s / (float)max(end - beg, 1);
}

// M[layer][k][h] = sum_c We[k,h*16+c] * ae[h*16+c]
__global__ void k_M(const float* __restrict__ We1, const float* __restrict__ ae1,
                    const float* __restrict__ We2, const float* __restrict__ ae2,
                    float* __restrict__ M) {
  int tid = threadIdx.x;
  if (tid >= 64) return;
  int layer = tid >> 5, kh = tid & 31;
  int k = kh >> 3, h = kh & 7;
  const float* We = layer ? We2 : We1;
  const float* ae = layer ? ae2 : ae1;
  float acc = 0.f;
  for (int c = 0; c < 16; ++c) acc += We[k * 128 + h * 16 + c] * ae[h * 16 + c];
  M[layer * 32 + k * 8 + h] = acc;
}

// ---------------- layer kernels ----------------

__global__ __launch_bounds__(256) void k_node1(const float* __restrict__ x,
    const float* __restrict__ W, const float* __restrict__ as_, const float* __restrict__ ad_,
    float* __restrict__ h, float* __restrict__ a_s, float* __restrict__ a_d, int N) {
  __shared__ float Wl[512];
  __shared__ float asl[128], adl[128];
  int tid = threadIdx.x;
  for (int i = tid; i < 512; i += 256) Wl[i] = W[i];
  if (tid < 128) { asl[tid] = as_[tid]; adl[tid] = ad_[tid]; }
  __syncthreads();
  int c = tid & 127, half = tid >> 7;
  for (int n0 = blockIdx.x * 2; n0 < N; n0 += gridDim.x * 2) {
    int n = n0 + half;
    if (n < N) {
      float4 xr = *reinterpret_cast<const float4*>(x + (size_t)n * 4);
      float hv = xr.x * Wl[c] + xr.y * Wl[128 + c] + xr.z * Wl[256 + c] + xr.w * Wl[384 + c];
      h[(size_t)n * 128 + c] = hv;
      float ps = hv * asl[c], pd = hv * adl[c];
      for (int o = 1; o < 16; o <<= 1) { ps += __shfl_xor(ps, o, 64); pd += __shfl_xor(pd, o, 64); }
      if ((c & 15) == 0) { a_s[n * 8 + (c >> 4)] = ps; a_d[n * 8 + (c >> 4)] = pd; }
    }
  }
}

// h = x @ W2, float4 register tile: thread = (node, 4 channels)
__global__ __launch_bounds__(256) void k_node2(const float* __restrict__ x,
    const float* __restrict__ W, const float* __restrict__ as_, const float* __restrict__ ad_,
    float* __restrict__ h, float* __restrict__ a_s, float* __restrict__ a_d, int N) {
  __shared__ float4 Wl[128 * 32];     // Wl[k*32+cg] = W[k][cg*4..cg*4+3]  (64 KiB)
  __shared__ float xl[8][128];
  __shared__ float asl[128], adl[128];
  int tid = threadIdx.x;
  for (int i = tid; i < 4096; i += 256) Wl[i] = reinterpret_cast<const float4*>(W)[i];
  if (tid < 128) { asl[tid] = as_[tid]; adl[tid] = ad_[tid]; }
  __syncthreads();
  int node = tid >> 5, cg = tid & 31;
  for (int n0 = blockIdx.x * 8; n0 < N; n0 += gridDim.x * 8) {
    __syncthreads();
    #pragma unroll
    for (int j = 0; j < 4; ++j) {
      int idx = tid + j * 256;
      int r = idx >> 7, cc = idx & 127;
      int nn = n0 + r;
      xl[r][cc] = (nn < N) ? x[(size_t)nn * 128 + cc] : 0.f;
    }
    __syncthreads();
    int nn = n0 + node;
    float4 acc = make_float4(0.f, 0.f, 0.f, 0.f);
    #pragma unroll 4
    for (int k = 0; k < 128; ++k) {
      float xv = xl[node][k];
      float4 wv = Wl[k * 32 + cg];
      acc.x += xv * wv.x; acc.y += xv * wv.y; acc.z += xv * wv.z; acc.w += xv * wv.w;
    }
    if (nn < N) {
      *reinterpret_cast<float4*>(h + (size_t)nn * 128 + cg * 4) = acc;
      float ps = acc.x * asl[cg * 4] + acc.y * asl[cg * 4 + 1] +
                 acc.z * asl[cg * 4 + 2] + acc.w * asl[cg * 4 + 3];
      float pd = acc.x * adl[cg * 4] + acc.y * adl[cg * 4 + 1] +
                 acc.z * adl[cg * 4 + 2] + acc.w * adl[cg * 4 + 3];
      ps += __shfl_xor(ps, 1, 64); ps += __shfl_xor(ps, 2, 64);
      pd += __shfl_xor(pd, 1, 64); pd += __shfl_xor(pd, 2, 64);
      if ((cg & 3) == 0) { a_s[nn * 8 + (cg >> 2)] = ps; a_d[nn * 8 + (cg >> 2)] = pd; }
    }
  }
}

// one wave per target node: fused edge-attention + ONLINE softmax aggregate.
// alpha computed inline: leaky(a_s[src][h] + a_d[tgt][h] + eaP[i].M[:,h]).
__global__ __launch_bounds__(256) void k_aggr(const int* __restrict__ csrc,
    const int* __restrict__ off, const float* __restrict__ a_s, const float* __restrict__ a_d,
    const float* __restrict__ eaP, const float* __restrict__ M,
    const float* __restrict__ h, const float* __restrict__ bias,
    float* __restrict__ xout, int N) {
  int wid = (blockIdx.x * blockDim.x + threadIdx.x) >> 6;
  if (wid >= N) return;
  int lane = threadIdx.x & 63;
  int head = lane >> 3;
  float M0 = M[head], M1 = M[8 + head], M2 = M[16 + head], M3 = M[24 + head];
  float ad = a_d[(size_t)wid * 8 + head];
  int beg = off[wid], end = off[wid + 1];
  float m = -1e30f, sum = 0.f, acc0 = 0.f, acc1 = 0.f;
  int i = beg;
  for (; i + 4 <= end; i += 4) {
    int s0 = csrc[i], s1 = csrc[i + 1], s2 = csrc[i + 2], s3 = csrc[i + 3];
    float4 e0 = *reinterpret_cast<const float4*>(eaP + (size_t)i * 4);
    float4 e1 = *reinterpret_cast<const float4*>(eaP + (size_t)(i + 1) * 4);
    float4 e2 = *reinterpret_cast<const float4*>(eaP + (size_t)(i + 2) * 4);
    float4 e3 = *reinterpret_cast<const float4*>(eaP + (size_t)(i + 3) * 4);
    float v0 = a_s[(size_t)s0 * 8 + head], v1 = a_s[(size_t)s1 * 8 + head];
    float v2 = a_s[(size_t)s2 * 8 + head], v3 = a_s[(size_t)s3 * 8 + head];
    float2 h0 = *reinterpret_cast<const float2*>(h + (size_t)s0 * 128 + lane * 2);
    float2 h1 = *reinterpret_cast<const float2*>(h + (size_t)s1 * 128 + lane * 2);
    float2 h2 = *reinterpret_cast<const float2*>(h + (size_t)s2 * 128 + lane * 2);
    float2 h3 = *reinterpret_cast<const float2*>(h + (size_t)s3 * 128 + lane * 2);
    float a0 = v0 + ad + e0.x * M0 + e0.y * M1 + e0.z * M2 + e0.w * M3;
    float a1 = v1 + ad + e1.x * M0 + e1.y * M1 + e1.z * M2 + e1.w * M3;
    float a2 = v2 + ad + e2.x * M0 + e2.y * M1 + e2.z * M2 + e2.w * M3;
    float a3 = v3 + ad + e3.x * M0 + e3.y * M1 + e3.z * M2 + e3.w * M3;
    a0 = a0 > 0.f ? a0 : NEG_SLOPE * a0;
    a1 = a1 > 0.f ? a1 : NEG_SLOPE * a1;
    a2 = a2 > 0.f ? a2 : NEG_SLOPE * a2;
    a3 = a3 > 0.f ? a3 : NEG_SLOPE * a3;
    float nm = fmaxf(fmaxf(fmaxf(a0, a1), fmaxf(a2, a3)), m);
    float r = __expf(m - nm);
    float x0 = __expf(a0 - nm), x1 = __expf(a1 - nm);
    float x2 = __expf(a2 - nm), x3 = __expf(a3 - nm);
    sum  = sum  * r + ((x0 + x1) + (x2 + x3));
    acc0 = acc0 * r + ((x0 * h0.x + x1 * h1.x) + (x2 * h2.x + x3 * h3.x));
    acc1 = acc1 * r + ((x0 * h0.y + x1 * h1.y) + (x2 * h2.y + x3 * h3.y));
    m = nm;
  }
  for (; i < end; ++i) {
    int s0 = csrc[i];
    float4 e0 = *reinterpret_cast<const float4*>(eaP + (size_t)i * 4);
    float2 h0 = *reinterpret_cast<const float2*>(h + (size_t)s0 * 128 + lane * 2);
    float a0 = a_s[(size_t)s0 * 8 + head] + ad + e0.x * M0 + e0.y * M1 + e0.z * M2 + e0.w * M3;
    a0 = a0 > 0.f ? a0 : NEG_SLOPE * a0;
    float nm = fmaxf(a0, m);
    float r = __expf(m - nm);
    float x0 = __expf(a0 - nm);
    sum  = sum  * r + x0;
    acc0 = acc0 * r + x0 * h0.x;
    acc1 = acc1 * r + x0 * h0.y;
    m = nm;
  }
  float inv = 1.f / (sum + 1e-16f);
  float o0 = fmaxf(acc0 * inv + bias[lane * 2], 0.f);
  float o1 = fmaxf(acc1 * inv + bias[lane * 2 + 1], 0.f);
  *reinterpret_cast<float2*>(xout + (size_t)wid * 128 + lane * 2) = make_float2(o0, o1);
}

// ---------------- pooling + FC ----------------

// batch is sorted: per-block register accumulate, flush atomics at boundaries
#define PROWS 128
__global__ __launch_bounds__(128) void k_pool(const float* __restrict__ x,
    const int* __restrict__ batch, float* __restrict__ pool, int* __restrict__ cntg, int N) {
  int c = threadIdx.x;
  int n0 = blockIdx.x * PROWS;
  if (n0 >= N) return;
  int nend = min(n0 + PROWS, N);
  float acc = 0.f; int cnt = 0; int g = batch[n0];
  for (int n = n0; n < nend; ++n) {
    int bn = batch[n];
    if (bn != g) {
      atomicAdd(&pool[(size_t)g * 128 + c], acc);
      if (c == 0) atomicAdd(&cntg[g], cnt);
      acc = 0.f; cnt = 0; g = bn;
    }
    acc += x[(size_t)n * 128 + c];
    cnt++;
  }
  atomicAdd(&pool[(size_t)g * 128 + c], acc);
  if (c == 0) atomicAdd(&cntg[g], cnt);
}

__global__ __launch_bounds__(128) void k_fc(const float* __restrict__ pool,
    const int* __restrict__ cntg, const float* __restrict__ fcw,
    const float* __restrict__ fcb, float* __restrict__ out, int G) {
  int g = blockIdx.x, c = threadIdx.x;
  __shared__ float r0[2], r1[2];
  float inv = 1.f / (float)max(cntg[g], 1);
  float v = pool[(size_t)g * 128 + c] * inv;
  float p0 = v * fcw[c * 2], p1 = v * fcw[c * 2 + 1];
  for (int o = 1; o < 64; o <<= 1) { p0 += __shfl_xor(p0, o, 64); p1 += __shfl_xor(p1, o, 64); }
  if ((c & 63) == 0) { r0[c >> 6] = p0; r1[c >> 6] = p1; }
  __syncthreads();
  if (c == 0) {
    out[g * 2]     = r0[0] + r0[1] + fcb[0];
    out[g * 2 + 1] = r1[0] + r1[1] + fcb[1];
  }
}

// ---------------- host ----------------

extern "C" void kernel_launch(void* const* d_in, const int* in_sizes, int n_in,
                              void* d_out, int out_size, void* d_ws, size_t ws_size,
                              hipStream_t stream) {
  const float* x     = (const float*)d_in[0];
  const int*   eidx  = (const int*)d_in[1];
  const int*   batch = (const int*)d_in[2];
  const float* eattr = (const float*)d_in[3];
  const float* W1  = (const float*)d_in[4];
  const float* as1 = (const float*)d_in[5];
  const float* ad1 = (const float*)d_in[6];
  const float* We1 = (const float*)d_in[7];
  const float* ae1 = (const float*)d_in[8];
  const float* b1  = (const float*)d_in[9];
  const float* W2  = (const float*)d_in[10];
  const float* as2 = (const float*)d_in[11];
  const float* ad2 = (const float*)d_in[12];
  const float* We2 = (const float*)d_in[13];
  const float* ae2 = (const float*)d_in[14];
  const float* b2  = (const float*)d_in[15];
  const float* fcw = (const float*)d_in[16];
  const float* fcb = (const float*)d_in[17];

  const int N  = in_sizes[2];
  const int E  = in_sizes[1] / 2;
  const int G  = out_size / 2;
  const int E2 = E + N;
  const int* srcI = eidx;
  const int* tgtI = eidx + E;

  char* w = (char*)d_ws;
  auto alloc = [&](size_t bytes) -> void* {
    void* p = (void*)w;
    w += (bytes + 255) & ~(size_t)255;
    return p;
  };
  int*   deg    = (int*)alloc((size_t)N * 8);        // deg + cur contiguous
  int*   cur    = deg + N;
  int*   off    = (int*)alloc((size_t)(N + 1) * 4);
  int*   csrc   = (int*)alloc((size_t)E2 * 4);
  int*   ceid   = (int*)alloc((size_t)E2 * 4);
  float* eaP    = (float*)alloc((size_t)E2 * 16);
  float* a_s    = (float*)alloc((size_t)N * 32);
  float* a_d    = (float*)alloc((size_t)N * 32);
  float* hbuf   = (float*)alloc((size_t)N * 512);
  float* xbuf   = (float*)alloc((size_t)N * 512);
  float* M      = (float*)alloc(256);
  float* pool   = (float*)alloc((size_t)G * 512 + (size_t)G * 4);  // pool + cntg contiguous
  int*   cntg   = (int*)(pool + (size_t)G * 128);

  hipMemsetAsync(deg, 0, (size_t)N * 8, stream);
  hipMemsetAsync(pool, 0, (size_t)G * 516, stream);

  k_deg<<<(E + 255) / 256, 256, 0, stream>>>(tgtI, deg, E);
  k_scan<<<1, 1024, 0, stream>>>(deg, off, N);
  k_fillself<<<(N + 255) / 256, 256, 0, stream>>>(off, csrc, ceid, E, N);
  k_filledge<<<(E + 255) / 256, 256, 0, stream>>>(srcI, tgtI, off, cur, csrc, ceid, E);
  k_permute<<<(E2 + 255) / 256, 256, 0, stream>>>(ceid, eattr, (float4*)eaP, E, E2);
  k_loopattr<<<(N * 4 + 255) / 256, 256, 0, stream>>>(off, eaP, N);
  k_M<<<1, 64, 0, stream>>>(We1, ae1, We2, ae2, M);

  // layer 1
  k_node1<<<(N + 1) / 2, 256, 0, stream>>>(x, W1, as1, ad1, hbuf, a_s, a_d, N);
  k_aggr<<<(N + 3) / 4, 256, 0, stream>>>(csrc, off, a_s, a_d, eaP, M, hbuf, b1, xbuf, N);

  // layer 2
  k_node2<<<1024, 256, 0, stream>>>(xbuf, W2, as2, ad2, hbuf, a_s, a_d, N);
  k_aggr<<<(N + 3) / 4, 256, 0, stream>>>(csrc, off, a_s, a_d, eaP, M + 32, hbuf, b2, xbuf, N);

  // pool + fc
  k_pool<<<(N + PROWS - 1) / PROWS, 128, 0, stream>>>(xbuf, batch, pool, cntg, N);
  k_fc<<<G, 128, 0, stream>>>(pool, cntg, fcw, fcb, (float*)d_out, G);
}

// Round 4
// 417.716 us; speedup vs baseline: 2.1695x; 1.0356x over previous
//
#include <hip/hip_runtime.h>

#define NEG_SLOPE 0.2f

// ---------------- graph preprocessing ----------------

__global__ void k_deg(const int* __restrict__ tgt, int* __restrict__ deg, int E) {
  int e = blockIdx.x * blockDim.x + threadIdx.x;
  if (e < E) atomicAdd(&deg[tgt[e]], 1);
}

// off[0]=0; off[i+1]=sum_{j<=i}(deg[j]+1). Single block, wave-shuffle scan.
// Tail: fill self-loop src into last slot of each node's CSR segment.
__global__ __launch_bounds__(1024) void k_scan(const int* __restrict__ deg,
                                               int* __restrict__ off,
                                               int* __restrict__ csrc, int n) {
  __shared__ int wsum[16];
  __shared__ int carry_s;
  int tid = threadIdx.x, lane = tid & 63, wv = tid >> 6;
  if (tid == 0) { carry_s = 0; off[0] = 0; }
  __syncthreads();
  for (int base = 0; base < n; base += 4096) {
    int i0 = base + tid * 4;
    int v[4];
    #pragma unroll
    for (int j = 0; j < 4; ++j) { int i = i0 + j; v[j] = (i < n) ? deg[i] + 1 : 0; }
    v[1] += v[0]; v[2] += v[1]; v[3] += v[2];
    int tsum = v[3];
    int sc = tsum;
    #pragma unroll
    for (int o = 1; o < 64; o <<= 1) { int t = __shfl_up(sc, o, 64); if (lane >= o) sc += t; }
    if (lane == 63) wsum[wv] = sc;
    __syncthreads();
    if (wv == 0 && lane < 16) {
      int ws = wsum[lane];
      #pragma unroll
      for (int o = 1; o < 16; o <<= 1) { int t = __shfl_up(ws, o, 64); if (lane >= o) ws += t; }
      wsum[lane] = ws;
    }
    __syncthreads();
    int excl = carry_s + (wv ? wsum[wv - 1] : 0) + sc - tsum;
    #pragma unroll
    for (int j = 0; j < 4; ++j) { int i = i0 + j; if (i < n) off[i + 1] = excl + v[j]; }
    __syncthreads();
    if (tid == 0) carry_s += wsum[15];
    __syncthreads();
  }
  __syncthreads();
  for (int i = tid; i < n; i += 1024) csrc[off[i + 1] - 1] = i;  // self-loop slot
}

// scatter edges into CSR: src id + permuted edge-attr row (coalesced eattr read)
__global__ void k_filledge(const int* __restrict__ src, const int* __restrict__ tgt,
                           const int* __restrict__ off, int* __restrict__ cur,
                           int* __restrict__ csrc, float4* __restrict__ eaP, int E) {
  int e = blockIdx.x * blockDim.x + threadIdx.x;
  if (e >= E) return;
  int t = tgt[e];
  int pos = off[t] + atomicAdd(&cur[t], 1);
  csrc[pos] = src[e];
  eaP[pos] = reinterpret_cast<const float4*>(src - src[0] * 0 + 0)[0], // placeholder avoided below
  eaP[pos] = make_float4(0.f, 0.f, 0.f, 0.f);
}

// (real filledge — see k_filledge2; kept single definition below)

__global__ void k_filledge2(const int* __restrict__ src, const int* __restrict__ tgt,
                            const float* __restrict__ eattr,
                            const int* __restrict__ off, int* __restrict__ cur,
                            int* __restrict__ csrc, float4* __restrict__ eaP, int E) {
  int e = blockIdx.x * blockDim.x + threadIdx.x;
  if (e >= E) return;
  int t = tgt[e];
  int pos = off[t] + atomicAdd(&cur[t], 1);
  csrc[pos] = src[e];
  eaP[pos] = reinterpret_cast<const float4*>(eattr)[e];
}

// self-slot attr = mean of the node's incoming eaP rows (0 if none)
__global__ void k_loopattr(const int* __restrict__ off, float* __restrict__ eaP, int N) {
  int idx = blockIdx.x * blockDim.x + threadIdx.x;
  int n = idx >> 2, c = idx & 3;
  if (n >= N) return;
  int beg = off[n], end = off[n + 1] - 1;  // exclude self slot
  float s = 0.f;
  for (int i = beg; i < end; ++i) s += eaP[(size_t)i * 4 + c];
  eaP[(size_t)end * 4 + c] = s / (float)max(end - beg, 1);
}

// M[layer][k][h] = sum_c We[k,h*16+c] * ae[h*16+c]
__global__ void k_M(const float* __restrict__ We1, const float* __restrict__ ae1,
                    const float* __restrict__ We2, const float* __restrict__ ae2,
                    float* __restrict__ M) {
  int tid = threadIdx.x;
  if (tid >= 64) return;
  int layer = tid >> 5, kh = tid & 31;
  int k = kh >> 3, h = kh & 7;
  const float* We = layer ? We2 : We1;
  const float* ae = layer ? ae2 : ae1;
  float acc = 0.f;
  for (int c = 0; c < 16; ++c) acc += We[k * 128 + h * 16 + c] * ae[h * 16 + c];
  M[layer * 32 + k * 8 + h] = acc;
}

// ---------------- layer kernels ----------------

// layer-1 node terms only (a_s, a_d) — h is recomputed on the fly in k_aggr1
__global__ __launch_bounds__(256) void k_node1(const float* __restrict__ x,
    const float* __restrict__ W, const float* __restrict__ as_, const float* __restrict__ ad_,
    float* __restrict__ a_s, float* __restrict__ a_d, int N) {
  __shared__ float Wl[512];
  __shared__ float asl[128], adl[128];
  int tid = threadIdx.x;
  for (int i = tid; i < 512; i += 256) Wl[i] = W[i];
  if (tid < 128) { asl[tid] = as_[tid]; adl[tid] = ad_[tid]; }
  __syncthreads();
  int c = tid & 127, half = tid >> 7;
  for (int n0 = blockIdx.x * 2; n0 < N; n0 += gridDim.x * 2) {
    int n = n0 + half;
    if (n < N) {
      float4 xr = *reinterpret_cast<const float4*>(x + (size_t)n * 4);
      float hv = xr.x * Wl[c] + xr.y * Wl[128 + c] + xr.z * Wl[256 + c] + xr.w * Wl[384 + c];
      float ps = hv * asl[c], pd = hv * adl[c];
      for (int o = 1; o < 16; o <<= 1) { ps += __shfl_xor(ps, o, 64); pd += __shfl_xor(pd, o, 64); }
      if ((c & 15) == 0) { a_s[n * 8 + (c >> 4)] = ps; a_d[n * 8 + (c >> 4)] = pd; }
    }
  }
}

// h = x @ W2, float4 register tile: thread = (node, 4 channels)
__global__ __launch_bounds__(256) void k_node2(const float* __restrict__ x,
    const float* __restrict__ W, const float* __restrict__ as_, const float* __restrict__ ad_,
    float* __restrict__ h, float* __restrict__ a_s, float* __restrict__ a_d, int N) {
  __shared__ float4 Wl[128 * 32];     // 64 KiB
  __shared__ float xl[8][128];
  __shared__ float asl[128], adl[128];
  int tid = threadIdx.x;
  for (int i = tid; i < 4096; i += 256) Wl[i] = reinterpret_cast<const float4*>(W)[i];
  if (tid < 128) { asl[tid] = as_[tid]; adl[tid] = ad_[tid]; }
  __syncthreads();
  int node = tid >> 5, cg = tid & 31;
  for (int n0 = blockIdx.x * 8; n0 < N; n0 += gridDim.x * 8) {
    __syncthreads();
    #pragma unroll
    for (int j = 0; j < 4; ++j) {
      int idx = tid + j * 256;
      int r = idx >> 7, cc = idx & 127;
      int nn = n0 + r;
      xl[r][cc] = (nn < N) ? x[(size_t)nn * 128 + cc] : 0.f;
    }
    __syncthreads();
    int nn = n0 + node;
    float4 acc = make_float4(0.f, 0.f, 0.f, 0.f);
    #pragma unroll 4
    for (int k = 0; k < 128; ++k) {
      float xv = xl[node][k];
      float4 wv = Wl[k * 32 + cg];
      acc.x += xv * wv.x; acc.y += xv * wv.y; acc.z += xv * wv.z; acc.w += xv * wv.w;
    }
    if (nn < N) {
      *reinterpret_cast<float4*>(h + (size_t)nn * 128 + cg * 4) = acc;
      float ps = acc.x * asl[cg * 4] + acc.y * asl[cg * 4 + 1] +
                 acc.z * asl[cg * 4 + 2] + acc.w * asl[cg * 4 + 3];
      float pd = acc.x * adl[cg * 4] + acc.y * adl[cg * 4 + 1] +
                 acc.z * adl[cg * 4 + 2] + acc.w * adl[cg * 4 + 3];
      ps += __shfl_xor(ps, 1, 64); ps += __shfl_xor(ps, 2, 64);
      pd += __shfl_xor(pd, 1, 64); pd += __shfl_xor(pd, 2, 64);
      if ((cg & 3) == 0) { a_s[nn * 8 + (cg >> 2)] = ps; a_d[nn * 8 + (cg >> 2)] = pd; }
    }
  }
}

// layer-1 aggregate: one wave per target; h[src] recomputed from x[src] (16 B row,
// L2-resident) instead of gathering 512 B. Plain exp (|alpha| <~ 1, softmax is
// shift-invariant -> matches reference to rounding).
__global__ __launch_bounds__(256) void k_aggr1(const int* __restrict__ csrc,
    const int* __restrict__ off, const float* __restrict__ a_s, const float* __restrict__ a_d,
    const float* __restrict__ eaP, const float* __restrict__ M,
    const float* __restrict__ x, const float* __restrict__ W,
    const float* __restrict__ bias, float* __restrict__ xout, int N) {
  int wid = (blockIdx.x * blockDim.x + threadIdx.x) >> 6;
  if (wid >= N) return;
  int lane = threadIdx.x & 63;
  int head = lane >> 3;
  float2 w0 = *reinterpret_cast<const float2*>(W + lane * 2);
  float2 w1 = *reinterpret_cast<const float2*>(W + 128 + lane * 2);
  float2 w2 = *reinterpret_cast<const float2*>(W + 256 + lane * 2);
  float2 w3 = *reinterpret_cast<const float2*>(W + 384 + lane * 2);
  float M0 = M[head], M1 = M[8 + head], M2 = M[16 + head], M3 = M[24 + head];
  float ad = a_d[(size_t)wid * 8 + head];
  int beg = off[wid], end = off[wid + 1];
  float sum = 0.f, acc0 = 0.f, acc1 = 0.f;
  int i = beg;
  for (; i + 4 <= end; i += 4) {
    int ib = __builtin_amdgcn_readfirstlane(i);
    int s0 = __builtin_amdgcn_readfirstlane(csrc[ib]);
    int s1 = __builtin_amdgcn_readfirstlane(csrc[ib + 1]);
    int s2 = __builtin_amdgcn_readfirstlane(csrc[ib + 2]);
    int s3 = __builtin_amdgcn_readfirstlane(csrc[ib + 3]);
    float4 e0 = *reinterpret_cast<const float4*>(eaP + (size_t)ib * 4);
    float4 e1 = *reinterpret_cast<const float4*>(eaP + (size_t)(ib + 1) * 4);
    float4 e2 = *reinterpret_cast<const float4*>(eaP + (size_t)(ib + 2) * 4);
    float4 e3 = *reinterpret_cast<const float4*>(eaP + (size_t)(ib + 3) * 4);
    float4 x0 = *reinterpret_cast<const float4*>(x + (size_t)s0 * 4);
    float4 x1 = *reinterpret_cast<const float4*>(x + (size_t)s1 * 4);
    float4 x2 = *reinterpret_cast<const float4*>(x + (size_t)s2 * 4);
    float4 x3 = *reinterpret_cast<const float4*>(x + (size_t)s3 * 4);
    float v0 = a_s[(size_t)s0 * 8 + head], v1 = a_s[(size_t)s1 * 8 + head];
    float v2 = a_s[(size_t)s2 * 8 + head], v3 = a_s[(size_t)s3 * 8 + head];
    float a0 = v0 + ad + e0.x * M0 + e0.y * M1 + e0.z * M2 + e0.w * M3;
    float a1 = v1 + ad + e1.x * M0 + e1.y * M1 + e1.z * M2 + e1.w * M3;
    float a2 = v2 + ad + e2.x * M0 + e2.y * M1 + e2.z * M2 + e2.w * M3;
    float a3 = v3 + ad + e3.x * M0 + e3.y * M1 + e3.z * M2 + e3.w * M3;
    a0 = a0 > 0.f ? a0 : NEG_SLOPE * a0;
    a1 = a1 > 0.f ? a1 : NEG_SLOPE * a1;
    a2 = a2 > 0.f ? a2 : NEG_SLOPE * a2;
    a3 = a3 > 0.f ? a3 : NEG_SLOPE * a3;
    float p0 = __expf(a0), p1 = __expf(a1), p2 = __expf(a2), p3 = __expf(a3);
    sum += (p0 + p1) + (p2 + p3);
    float h0x = x0.x * w0.x + x0.y * w1.x + x0.z * w2.x + x0.w * w3.x;
    float h0y = x0.x * w0.y + x0.y * w1.y + x0.z * w2.y + x0.w * w3.y;
    float h1x = x1.x * w0.x + x1.y * w1.x + x1.z * w2.x + x1.w * w3.x;
    float h1y = x1.x * w0.y + x1.y * w1.y + x1.z * w2.y + x1.w * w3.y;
    float h2x = x2.x * w0.x + x2.y * w1.x + x2.z * w2.x + x2.w * w3.x;
    float h2y = x2.x * w0.y + x2.y * w1.y + x2.z * w2.y + x2.w * w3.y;
    float h3x = x3.x * w0.x + x3.y * w1.x + x3.z * w2.x + x3.w * w3.x;
    float h3y = x3.x * w0.y + x3.y * w1.y + x3.z * w2.y + x3.w * w3.y;
    acc0 += (p0 * h0x + p1 * h1x) + (p2 * h2x + p3 * h3x);
    acc1 += (p0 * h0y + p1 * h1y) + (p2 * h2y + p3 * h3y);
  }
  for (; i < end; ++i) {
    int ib = __builtin_amdgcn_readfirstlane(i);
    int s0 = __builtin_amdgcn_readfirstlane(csrc[ib]);
    float4 e0 = *reinterpret_cast<const float4*>(eaP + (size_t)ib * 4);
    float4 x0 = *reinterpret_cast<const float4*>(x + (size_t)s0 * 4);
    float a0 = a_s[(size_t)s0 * 8 + head] + ad + e0.x * M0 + e0.y * M1 + e0.z * M2 + e0.w * M3;
    a0 = a0 > 0.f ? a0 : NEG_SLOPE * a0;
    float p0 = __expf(a0);
    sum += p0;
    acc0 += p0 * (x0.x * w0.x + x0.y * w1.x + x0.z * w2.x + x0.w * w3.x);
    acc1 += p0 * (x0.x * w0.y + x0.y * w1.y + x0.z * w2.y + x0.w * w3.y);
  }
  float inv = 1.f / (sum + 1e-16f);
  float o0 = fmaxf(acc0 * inv + bias[lane * 2], 0.f);
  float o1 = fmaxf(acc1 * inv + bias[lane * 2 + 1], 0.f);
  *reinterpret_cast<float2*>(xout + (size_t)wid * 128 + lane * 2) = make_float2(o0, o1);
}

// layer-2 aggregate: gathers 512 B h rows; unroll 8, plain exp
__global__ __launch_bounds__(256) void k_aggr2(const int* __restrict__ csrc,
    const int* __restrict__ off, const float* __restrict__ a_s, const float* __restrict__ a_d,
    const float* __restrict__ eaP, const float* __restrict__ M,
    const float* __restrict__ h, const float* __restrict__ bias,
    float* __restrict__ xout, int N) {
  int wid = (blockIdx.x * blockDim.x + threadIdx.x) >> 6;
  if (wid >= N) return;
  int lane = threadIdx.x & 63;
  int head = lane >> 3;
  float M0 = M[head], M1 = M[8 + head], M2 = M[16 + head], M3 = M[24 + head];
  float ad = a_d[(size_t)wid * 8 + head];
  int beg = off[wid], end = off[wid + 1];
  float sum = 0.f, acc0 = 0.f, acc1 = 0.f;
  int i = beg;
  for (; i + 8 <= end; i += 8) {
    int ib = __builtin_amdgcn_readfirstlane(i);
    int s[8]; float4 e[8]; float2 hv[8]; float v[8];
    #pragma unroll
    for (int j = 0; j < 8; ++j) s[j] = csrc[ib + j];
    #pragma unroll
    for (int j = 0; j < 8; ++j) e[j] = *reinterpret_cast<const float4*>(eaP + (size_t)(ib + j) * 4);
    #pragma unroll
    for (int j = 0; j < 8; ++j) hv[j] = *reinterpret_cast<const float2*>(h + (size_t)s[j] * 128 + lane * 2);
    #pragma unroll
    for (int j = 0; j < 8; ++j) v[j] = a_s[(size_t)s[j] * 8 + head];
    #pragma unroll
    for (int j = 0; j < 8; ++j) {
      float a = v[j] + ad + e[j].x * M0 + e[j].y * M1 + e[j].z * M2 + e[j].w * M3;
      a = a > 0.f ? a : NEG_SLOPE * a;
      float p = __expf(a);
      sum += p;
      acc0 += p * hv[j].x;
      acc1 += p * hv[j].y;
    }
  }
  for (; i < end; ++i) {
    int ib = __builtin_amdgcn_readfirstlane(i);
    int s0 = csrc[ib];
    float4 e0 = *reinterpret_cast<const float4*>(eaP + (size_t)ib * 4);
    float2 h0 = *reinterpret_cast<const float2*>(h + (size_t)s0 * 128 + lane * 2);
    float a0 = a_s[(size_t)s0 * 8 + head] + ad + e0.x * M0 + e0.y * M1 + e0.z * M2 + e0.w * M3;
    a0 = a0 > 0.f ? a0 : NEG_SLOPE * a0;
    float p0 = __expf(a0);
    sum += p0;
    acc0 += p0 * h0.x;
    acc1 += p0 * h0.y;
  }
  float inv = 1.f / (sum + 1e-16f);
  float o0 = fmaxf(acc0 * inv + bias[lane * 2], 0.f);
  float o1 = fmaxf(acc1 * inv + bias[lane * 2 + 1], 0.f);
  *reinterpret_cast<float2*>(xout + (size_t)wid * 128 + lane * 2) = make_float2(o0, o1);
}

// ---------------- pooling + FC ----------------

#define PROWS 128
__global__ __launch_bounds__(128) void k_pool(const float* __restrict__ x,
    const int* __restrict__ batch, float* __restrict__ pool, int* __restrict__ cntg, int N) {
  int c = threadIdx.x;
  int n0 = blockIdx.x * PROWS;
  if (n0 >= N) return;
  int nend = min(n0 + PROWS, N);
  float acc = 0.f; int cnt = 0; int g = batch[n0];
  for (int n = n0; n < nend; ++n) {
    int bn = batch[n];
    if (bn != g) {
      atomicAdd(&pool[(size_t)g * 128 + c], acc);
      if (c == 0) atomicAdd(&cntg[g], cnt);
      acc = 0.f; cnt = 0; g = bn;
    }
    acc += x[(size_t)n * 128 + c];
    cnt++;
  }
  atomicAdd(&pool[(size_t)g * 128 + c], acc);
  if (c == 0) atomicAdd(&cntg[g], cnt);
}

__global__ __launch_bounds__(128) void k_fc(const float* __restrict__ pool,
    const int* __restrict__ cntg, const float* __restrict__ fcw,
    const float* __restrict__ fcb, float* __restrict__ out, int G) {
  int g = blockIdx.x, c = threadIdx.x;
  __shared__ float r0[2], r1[2];
  float inv = 1.f / (float)max(cntg[g], 1);
  float v = pool[(size_t)g * 128 + c] * inv;
  float p0 = v * fcw[c * 2], p1 = v * fcw[c * 2 + 1];
  for (int o = 1; o < 64; o <<= 1) { p0 += __shfl_xor(p0, o, 64); p1 += __shfl_xor(p1, o, 64); }
  if ((c & 63) == 0) { r0[c >> 6] = p0; r1[c >> 6] = p1; }
  __syncthreads();
  if (c == 0) {
    out[g * 2]     = r0[0] + r0[1] + fcb[0];
    out[g * 2 + 1] = r1[0] + r1[1] + fcb[1];
  }
}

// ---------------- host ----------------

extern "C" void kernel_launch(void* const* d_in, const int* in_sizes, int n_in,
                              void* d_out, int out_size, void* d_ws, size_t ws_size,
                              hipStream_t stream) {
  const float* x     = (const float*)d_in[0];
  const int*   eidx  = (const int*)d_in[1];
  const int*   batch = (const int*)d_in[2];
  const float* eattr = (const float*)d_in[3];
  const float* W1  = (const float*)d_in[4];
  const float* as1 = (const float*)d_in[5];
  const float* ad1 = (const float*)d_in[6];
  const float* We1 = (const float*)d_in[7];
  const float* ae1 = (const float*)d_in[8];
  const float* b1  = (const float*)d_in[9];
  const float* W2  = (const float*)d_in[10];
  const float* as2 = (const float*)d_in[11];
  const float* ad2 = (const float*)d_in[12];
  const float* We2 = (const float*)d_in[13];
  const float* ae2 = (const float*)d_in[14];
  const float* b2  = (const float*)d_in[15];
  const float* fcw = (const float*)d_in[16];
  const float* fcb = (const float*)d_in[17];

  const int N  = in_sizes[2];
  const int E  = in_sizes[1] / 2;
  const int G  = out_size / 2;
  const int E2 = E + N;
  const int* srcI = eidx;
  const int* tgtI = eidx + E;

  char* w = (char*)d_ws;
  auto alloc = [&](size_t bytes) -> void* {
    void* p = (void*)w;
    w += (bytes + 255) & ~(size_t)255;
    return p;
  };
  int*   deg    = (int*)alloc((size_t)N * 8);        // deg + cur contiguous
  int*   cur    = deg + N;
  int*   off    = (int*)alloc((size_t)(N + 1) * 4);
  int*   csrc   = (int*)alloc((size_t)E2 * 4);
  float* eaP    = (float*)alloc((size_t)E2 * 16);
  float* a_s    = (float*)alloc((size_t)N * 32);
  float* a_d    = (float*)alloc((size_t)N * 32);
  float* hbuf   = (float*)alloc((size_t)N * 512);
  float* xbuf   = (float*)alloc((size_t)N * 512);
  float* M      = (float*)alloc(256);
  float* pool   = (float*)alloc((size_t)G * 512 + (size_t)G * 4);
  int*   cntg   = (int*)(pool + (size_t)G * 128);

  hipMemsetAsync(deg, 0, (size_t)N * 8, stream);
  hipMemsetAsync(pool, 0, (size_t)G * 516, stream);

  k_deg<<<(E + 255) / 256, 256, 0, stream>>>(tgtI, deg, E);
  k_scan<<<1, 1024, 0, stream>>>(deg, off, csrc, N);
  k_filledge2<<<(E + 255) / 256, 256, 0, stream>>>(srcI, tgtI, eattr, off, cur, csrc,
                                                   (float4*)eaP, E);
  k_loopattr<<<(N * 4 + 255) / 256, 256, 0, stream>>>(off, eaP, N);
  k_M<<<1, 64, 0, stream>>>(We1, ae1, We2, ae2, M);

  // layer 1 (h recomputed in aggr from x)
  k_node1<<<1024, 256, 0, stream>>>(x, W1, as1, ad1, a_s, a_d, N);
  k_aggr1<<<(N + 3) / 4, 256, 0, stream>>>(csrc, off, a_s, a_d, eaP, M, x, W1, b1, xbuf, N);

  // layer 2
  k_node2<<<1024, 256, 0, stream>>>(xbuf, W2, as2, ad2, hbuf, a_s, a_d, N);
  k_aggr2<<<(N + 3) / 4, 256, 0, stream>>>(csrc, off, a_s, a_d, eaP, M + 32, hbuf, b2, xbuf, N);

  // pool + fc
  k_pool<<<(N + PROWS - 1) / PROWS, 128, 0, stream>>>(xbuf, batch, pool, cntg, N);
  k_fc<<<G, 128, 0, stream>>>(pool, cntg, fcw, fcb, (float*)d_out, G);
}

// Round 5
// 331.942 us; speedup vs baseline: 2.7301x; 1.2584x over previous
//
#include <hip/hip_runtime.h>

#define NEG_SLOPE 0.2f

__device__ __forceinline__ unsigned short f2bf(float f) {
  unsigned u = __builtin_bit_cast(unsigned, f);
  unsigned r = u + 0x7FFFu + ((u >> 16) & 1u);   // round-to-nearest-even
  return (unsigned short)(r >> 16);
}

// ---------------- graph preprocessing ----------------

__global__ void k_deg(const int* __restrict__ tgt, int* __restrict__ deg, int E) {
  int e = blockIdx.x * blockDim.x + threadIdx.x;
  if (e < E) atomicAdd(&deg[tgt[e]], 1);
}

// phase 1: per-block sums of (deg[i]+1) over 256-element chunks
__global__ __launch_bounds__(256) void k_bsum(const int* __restrict__ deg,
                                              int* __restrict__ bsum, int n) {
  __shared__ int ws[4];
  int i = blockIdx.x * 256 + threadIdx.x;
  int lane = threadIdx.x & 63, wv = threadIdx.x >> 6;
  int v = (i < n) ? deg[i] + 1 : 0;
  #pragma unroll
  for (int o = 1; o < 64; o <<= 1) v += __shfl_xor(v, o, 64);
  if (lane == 0) ws[wv] = v;
  __syncthreads();
  if (threadIdx.x == 0) bsum[blockIdx.x] = ws[0] + ws[1] + ws[2] + ws[3];
}

// phase 2: single block, exclusive scan of nb (<=1024) block sums
__global__ __launch_bounds__(1024) void k_bscan(int* __restrict__ bsum, int nb) {
  __shared__ int wsum[16];
  int tid = threadIdx.x, lane = tid & 63, wv = tid >> 6;
  int v = (tid < nb) ? bsum[tid] : 0;
  int sc = v;
  #pragma unroll
  for (int o = 1; o < 64; o <<= 1) { int t = __shfl_up(sc, o, 64); if (lane >= o) sc += t; }
  if (lane == 63) wsum[wv] = sc;
  __syncthreads();
  if (wv == 0 && lane < 16) {
    int ws = wsum[lane];
    #pragma unroll
    for (int o = 1; o < 16; o <<= 1) { int t = __shfl_up(ws, o, 64); if (lane >= o) ws += t; }
    wsum[lane] = ws;
  }
  __syncthreads();
  int excl = (wv ? wsum[wv - 1] : 0) + sc - v;
  if (tid < nb) bsum[tid] = excl;
}

// phase 3: per-block scan -> off[i+1]; fill self-loop src in last CSR slot
__global__ __launch_bounds__(256) void k_off(const int* __restrict__ deg,
                                             const int* __restrict__ bsum,
                                             int* __restrict__ off,
                                             int* __restrict__ csrc, int n) {
  __shared__ int ws[4];
  int i = blockIdx.x * 256 + threadIdx.x;
  int lane = threadIdx.x & 63, wv = threadIdx.x >> 6;
  int v = (i < n) ? deg[i] + 1 : 0;
  int sc = v;
  #pragma unroll
  for (int o = 1; o < 64; o <<= 1) { int t = __shfl_up(sc, o, 64); if (lane >= o) sc += t; }
  if (lane == 63) ws[wv] = sc;
  __syncthreads();
  int pre = bsum[blockIdx.x];
  #pragma unroll
  for (int w = 0; w < 3; ++w) if (wv > w) pre += ws[w];
  int incl = pre + sc;
  if (i < n) {
    off[i + 1] = incl;
    csrc[incl - 1] = i;          // self-loop slot
  }
  if (i == 0) off[0] = 0;
}

// scatter edges into CSR: src id + permuted edge-attr row (coalesced eattr read)
__global__ void k_filledge(const int* __restrict__ src, const int* __restrict__ tgt,
                           const float* __restrict__ eattr,
                           const int* __restrict__ off, int* __restrict__ cur,
                           int* __restrict__ csrc, float4* __restrict__ eaP, int E) {
  int e = blockIdx.x * blockDim.x + threadIdx.x;
  if (e >= E) return;
  int t = tgt[e];
  int pos = off[t] + atomicAdd(&cur[t], 1);
  csrc[pos] = src[e];
  eaP[pos] = reinterpret_cast<const float4*>(eattr)[e];
}

// self-slot attr = mean of the node's incoming eaP rows (0 if none)
__global__ void k_loopattr(const int* __restrict__ off, float* __restrict__ eaP, int N) {
  int idx = blockIdx.x * blockDim.x + threadIdx.x;
  int n = idx >> 2, c = idx & 3;
  if (n >= N) return;
  int beg = off[n], end = off[n + 1] - 1;  // exclude self slot
  float s = 0.f;
  for (int i = beg; i < end; ++i) s += eaP[(size_t)i * 4 + c];
  eaP[(size_t)end * 4 + c] = s / (float)max(end - beg, 1);
}

// M[layer][k][h] = sum_c We[k,h*16+c] * ae[h*16+c]
__global__ void k_M(const float* __restrict__ We1, const float* __restrict__ ae1,
                    const float* __restrict__ We2, const float* __restrict__ ae2,
                    float* __restrict__ M) {
  int tid = threadIdx.x;
  if (tid >= 64) return;
  int layer = tid >> 5, kh = tid & 31;
  int k = kh >> 3, h = kh & 7;
  const float* We = layer ? We2 : We1;
  const float* ae = layer ? ae2 : ae1;
  float acc = 0.f;
  for (int c = 0; c < 16; ++c) acc += We[k * 128 + h * 16 + c] * ae[h * 16 + c];
  M[layer * 32 + k * 8 + h] = acc;
}

// ---------------- layer kernels ----------------

// layer-1 node terms only (a_s, a_d) — h recomputed on the fly in k_aggr1
__global__ __launch_bounds__(256) void k_node1(const float* __restrict__ x,
    const float* __restrict__ W, const float* __restrict__ as_, const float* __restrict__ ad_,
    float* __restrict__ a_s, float* __restrict__ a_d, int N) {
  __shared__ float Wl[512];
  __shared__ float asl[128], adl[128];
  int tid = threadIdx.x;
  for (int i = tid; i < 512; i += 256) Wl[i] = W[i];
  if (tid < 128) { asl[tid] = as_[tid]; adl[tid] = ad_[tid]; }
  __syncthreads();
  int c = tid & 127, half = tid >> 7;
  for (int n0 = blockIdx.x * 2; n0 < N; n0 += gridDim.x * 2) {
    int n = n0 + half;
    if (n < N) {
      float4 xr = *reinterpret_cast<const float4*>(x + (size_t)n * 4);
      float hv = xr.x * Wl[c] + xr.y * Wl[128 + c] + xr.z * Wl[256 + c] + xr.w * Wl[384 + c];
      float ps = hv * asl[c], pd = hv * adl[c];
      for (int o = 1; o < 16; o <<= 1) { ps += __shfl_xor(ps, o, 64); pd += __shfl_xor(pd, o, 64); }
      if ((c & 15) == 0) { a_s[n * 8 + (c >> 4)] = ps; a_d[n * 8 + (c >> 4)] = pd; }
    }
  }
}

// h2 = x @ W2 -> packed bf16 (only consumer is aggr2's gather); a_s/a_d from f32 acc
__global__ __launch_bounds__(256) void k_node2(const float* __restrict__ x,
    const float* __restrict__ W, const float* __restrict__ as_, const float* __restrict__ ad_,
    unsigned short* __restrict__ h16, float* __restrict__ a_s, float* __restrict__ a_d, int N) {
  __shared__ float4 Wl[128 * 32];     // 64 KiB
  __shared__ float xl[8][128];
  __shared__ float asl[128], adl[128];
  int tid = threadIdx.x;
  for (int i = tid; i < 4096; i += 256) Wl[i] = reinterpret_cast<const float4*>(W)[i];
  if (tid < 128) { asl[tid] = as_[tid]; adl[tid] = ad_[tid]; }
  __syncthreads();
  int node = tid >> 5, cg = tid & 31;
  for (int n0 = blockIdx.x * 8; n0 < N; n0 += gridDim.x * 8) {
    __syncthreads();
    #pragma unroll
    for (int j = 0; j < 4; ++j) {
      int idx = tid + j * 256;
      int r = idx >> 7, cc = idx & 127;
      int nn = n0 + r;
      xl[r][cc] = (nn < N) ? x[(size_t)nn * 128 + cc] : 0.f;
    }
    __syncthreads();
    int nn = n0 + node;
    float4 acc = make_float4(0.f, 0.f, 0.f, 0.f);
    #pragma unroll 4
    for (int k = 0; k < 128; ++k) {
      float xv = xl[node][k];
      float4 wv = Wl[k * 32 + cg];
      acc.x += xv * wv.x; acc.y += xv * wv.y; acc.z += xv * wv.z; acc.w += xv * wv.w;
    }
    if (nn < N) {
      ushort4 pk;
      pk.x = f2bf(acc.x); pk.y = f2bf(acc.y); pk.z = f2bf(acc.z); pk.w = f2bf(acc.w);
      *reinterpret_cast<ushort4*>(h16 + (size_t)nn * 128 + cg * 4) = pk;
      float ps = acc.x * asl[cg * 4] + acc.y * asl[cg * 4 + 1] +
                 acc.z * asl[cg * 4 + 2] + acc.w * asl[cg * 4 + 3];
      float pd = acc.x * adl[cg * 4] + acc.y * adl[cg * 4 + 1] +
                 acc.z * adl[cg * 4 + 2] + acc.w * adl[cg * 4 + 3];
      ps += __shfl_xor(ps, 1, 64); ps += __shfl_xor(ps, 2, 64);
      pd += __shfl_xor(pd, 1, 64); pd += __shfl_xor(pd, 2, 64);
      if ((cg & 3) == 0) { a_s[nn * 8 + (cg >> 2)] = ps; a_d[nn * 8 + (cg >> 2)] = pd; }
    }
  }
}

// layer-1 aggregate: h[src] recomputed from x[src] (16 B, L2-resident). Plain exp.
__global__ __launch_bounds__(256) void k_aggr1(const int* __restrict__ csrc,
    const int* __restrict__ off, const float* __restrict__ a_s, const float* __restrict__ a_d,
    const float* __restrict__ eaP, const float* __restrict__ M,
    const float* __restrict__ x, const float* __restrict__ W,
    const float* __restrict__ bias, float* __restrict__ xout, int N) {
  int wid = (blockIdx.x * blockDim.x + threadIdx.x) >> 6;
  if (wid >= N) return;
  int lane = threadIdx.x & 63;
  int head = lane >> 3;
  float2 w0 = *reinterpret_cast<const float2*>(W + lane * 2);
  float2 w1 = *reinterpret_cast<const float2*>(W + 128 + lane * 2);
  float2 w2 = *reinterpret_cast<const float2*>(W + 256 + lane * 2);
  float2 w3 = *reinterpret_cast<const float2*>(W + 384 + lane * 2);
  float M0 = M[head], M1 = M[8 + head], M2 = M[16 + head], M3 = M[24 + head];
  float ad = a_d[(size_t)wid * 8 + head];
  int beg = off[wid], end = off[wid + 1];
  float sum = 0.f, acc0 = 0.f, acc1 = 0.f;
  int i = beg;
  for (; i + 4 <= end; i += 4) {
    int ib = __builtin_amdgcn_readfirstlane(i);
    int s0 = __builtin_amdgcn_readfirstlane(csrc[ib]);
    int s1 = __builtin_amdgcn_readfirstlane(csrc[ib + 1]);
    int s2 = __builtin_amdgcn_readfirstlane(csrc[ib + 2]);
    int s3 = __builtin_amdgcn_readfirstlane(csrc[ib + 3]);
    float4 e0 = *reinterpret_cast<const float4*>(eaP + (size_t)ib * 4);
    float4 e1 = *reinterpret_cast<const float4*>(eaP + (size_t)(ib + 1) * 4);
    float4 e2 = *reinterpret_cast<const float4*>(eaP + (size_t)(ib + 2) * 4);
    float4 e3 = *reinterpret_cast<const float4*>(eaP + (size_t)(ib + 3) * 4);
    float4 x0 = *reinterpret_cast<const float4*>(x + (size_t)s0 * 4);
    float4 x1 = *reinterpret_cast<const float4*>(x + (size_t)s1 * 4);
    float4 x2 = *reinterpret_cast<const float4*>(x + (size_t)s2 * 4);
    float4 x3 = *reinterpret_cast<const float4*>(x + (size_t)s3 * 4);
    float v0 = a_s[(size_t)s0 * 8 + head], v1 = a_s[(size_t)s1 * 8 + head];
    float v2 = a_s[(size_t)s2 * 8 + head], v3 = a_s[(size_t)s3 * 8 + head];
    float a0 = v0 + ad + e0.x * M0 + e0.y * M1 + e0.z * M2 + e0.w * M3;
    float a1 = v1 + ad + e1.x * M0 + e1.y * M1 + e1.z * M2 + e1.w * M3;
    float a2 = v2 + ad + e2.x * M0 + e2.y * M1 + e2.z * M2 + e2.w * M3;
    float a3 = v3 + ad + e3.x * M0 + e3.y * M1 + e3.z * M2 + e3.w * M3;
    a0 = a0 > 0.f ? a0 : NEG_SLOPE * a0;
    a1 = a1 > 0.f ? a1 : NEG_SLOPE * a1;
    a2 = a2 > 0.f ? a2 : NEG_SLOPE * a2;
    a3 = a3 > 0.f ? a3 : NEG_SLOPE * a3;
    float p0 = __expf(a0), p1 = __expf(a1), p2 = __expf(a2), p3 = __expf(a3);
    sum += (p0 + p1) + (p2 + p3);
    float h0x = x0.x * w0.x + x0.y * w1.x + x0.z * w2.x + x0.w * w3.x;
    float h0y = x0.x * w0.y + x0.y * w1.y + x0.z * w2.y + x0.w * w3.y;
    float h1x = x1.x * w0.x + x1.y * w1.x + x1.z * w2.x + x1.w * w3.x;
    float h1y = x1.x * w0.y + x1.y * w1.y + x1.z * w2.y + x1.w * w3.y;
    float h2x = x2.x * w0.x + x2.y * w1.x + x2.z * w2.x + x2.w * w3.x;
    float h2y = x2.x * w0.y + x2.y * w1.y + x2.z * w2.y + x2.w * w3.y;
    float h3x = x3.x * w0.x + x3.y * w1.x + x3.z * w2.x + x3.w * w3.x;
    float h3y = x3.x * w0.y + x3.y * w1.y + x3.z * w2.y + x3.w * w3.y;
    acc0 += (p0 * h0x + p1 * h1x) + (p2 * h2x + p3 * h3x);
    acc1 += (p0 * h0y + p1 * h1y) + (p2 * h2y + p3 * h3y);
  }
  for (; i < end; ++i) {
    int ib = __builtin_amdgcn_readfirstlane(i);
    int s0 = __builtin_amdgcn_readfirstlane(csrc[ib]);
    float4 e0 = *reinterpret_cast<const float4*>(eaP + (size_t)ib * 4);
    float4 x0 = *reinterpret_cast<const float4*>(x + (size_t)s0 * 4);
    float a0 = a_s[(size_t)s0 * 8 + head] + ad + e0.x * M0 + e0.y * M1 + e0.z * M2 + e0.w * M3;
    a0 = a0 > 0.f ? a0 : NEG_SLOPE * a0;
    float p0 = __expf(a0);
    sum += p0;
    acc0 += p0 * (x0.x * w0.x + x0.y * w1.x + x0.z * w2.x + x0.w * w3.x);
    acc1 += p0 * (x0.x * w0.y + x0.y * w1.y + x0.z * w2.y + x0.w * w3.y);
  }
  float inv = 1.f / (sum + 1e-16f);
  float o0 = fmaxf(acc0 * inv + bias[lane * 2], 0.f);
  float o1 = fmaxf(acc1 * inv + bias[lane * 2 + 1], 0.f);
  *reinterpret_cast<float2*>(xout + (size_t)wid * 128 + lane * 2) = make_float2(o0, o1);
}

// layer-2 aggregate: gathers 256 B bf16 h rows; unroll 8, plain exp
__global__ __launch_bounds__(256) void k_aggr2(const int* __restrict__ csrc,
    const int* __restrict__ off, const float* __restrict__ a_s, const float* __restrict__ a_d,
    const float* __restrict__ eaP, const float* __restrict__ M,
    const unsigned short* __restrict__ h16, const float* __restrict__ bias,
    float* __restrict__ xout, int N) {
  int wid = (blockIdx.x * blockDim.x + threadIdx.x) >> 6;
  if (wid >= N) return;
  int lane = threadIdx.x & 63;
  int head = lane >> 3;
  float M0 = M[head], M1 = M[8 + head], M2 = M[16 + head], M3 = M[24 + head];
  float ad = a_d[(size_t)wid * 8 + head];
  int beg = off[wid], end = off[wid + 1];
  float sum = 0.f, acc0 = 0.f, acc1 = 0.f;
  int i = beg;
  for (; i + 8 <= end; i += 8) {
    int ib = __builtin_amdgcn_readfirstlane(i);
    int s[8]; float4 e[8]; unsigned hu[8]; float v[8];
    #pragma unroll
    for (int j = 0; j < 8; ++j) s[j] = csrc[ib + j];
    #pragma unroll
    for (int j = 0; j < 8; ++j) e[j] = *reinterpret_cast<const float4*>(eaP + (size_t)(ib + j) * 4);
    #pragma unroll
    for (int j = 0; j < 8; ++j)
      hu[j] = *reinterpret_cast<const unsigned*>(h16 + (size_t)s[j] * 128 + lane * 2);
    #pragma unroll
    for (int j = 0; j < 8; ++j) v[j] = a_s[(size_t)s[j] * 8 + head];
    #pragma unroll
    for (int j = 0; j < 8; ++j) {
      float a = v[j] + ad + e[j].x * M0 + e[j].y * M1 + e[j].z * M2 + e[j].w * M3;
      a = a > 0.f ? a : NEG_SLOPE * a;
      float p = __expf(a);
      sum += p;
      acc0 += p * __builtin_bit_cast(float, hu[j] << 16);
      acc1 += p * __builtin_bit_cast(float, hu[j] & 0xFFFF0000u);
    }
  }
  for (; i < end; ++i) {
    int ib = __builtin_amdgcn_readfirstlane(i);
    int s0 = csrc[ib];
    float4 e0 = *reinterpret_cast<const float4*>(eaP + (size_t)ib * 4);
    unsigned hu = *reinterpret_cast<const unsigned*>(h16 + (size_t)s0 * 128 + lane * 2);
    float a0 = a_s[(size_t)s0 * 8 + head] + ad + e0.x * M0 + e0.y * M1 + e0.z * M2 + e0.w * M3;
    a0 = a0 > 0.f ? a0 : NEG_SLOPE * a0;
    float p0 = __expf(a0);
    sum += p0;
    acc0 += p0 * __builtin_bit_cast(float, hu << 16);
    acc1 += p0 * __builtin_bit_cast(float, hu & 0xFFFF0000u);
  }
  float inv = 1.f / (sum + 1e-16f);
  float o0 = fmaxf(acc0 * inv + bias[lane * 2], 0.f);
  float o1 = fmaxf(acc1 * inv + bias[lane * 2 + 1], 0.f);
  *reinterpret_cast<float2*>(xout + (size_t)wid * 128 + lane * 2) = make_float2(o0, o1);
}

// ---------------- pooling + FC ----------------

#define PROWS 128
__global__ __launch_bounds__(128) void k_pool(const float* __restrict__ x,
    const int* __restrict__ batch, float* __restrict__ pool, int* __restrict__ cntg, int N) {
  int c = threadIdx.x;
  int n0 = blockIdx.x * PROWS;
  if (n0 >= N) return;
  int nend = min(n0 + PROWS, N);
  float acc = 0.f; int cnt = 0; int g = batch[n0];
  for (int n = n0; n < nend; ++n) {
    int bn = batch[n];
    if (bn != g) {
      atomicAdd(&pool[(size_t)g * 128 + c], acc);
      if (c == 0) atomicAdd(&cntg[g], cnt);
      acc = 0.f; cnt = 0; g = bn;
    }
    acc += x[(size_t)n * 128 + c];
    cnt++;
  }
  atomicAdd(&pool[(size_t)g * 128 + c], acc);
  if (c == 0) atomicAdd(&cntg[g], cnt);
}

__global__ __launch_bounds__(128) void k_fc(const float* __restrict__ pool,
    const int* __restrict__ cntg, const float* __restrict__ fcw,
    const float* __restrict__ fcb, float* __restrict__ out, int G) {
  int g = blockIdx.x, c = threadIdx.x;
  __shared__ float r0[2], r1[2];
  float inv = 1.f / (float)max(cntg[g], 1);
  float v = pool[(size_t)g * 128 + c] * inv;
  float p0 = v * fcw[c * 2], p1 = v * fcw[c * 2 + 1];
  for (int o = 1; o < 64; o <<= 1) { p0 += __shfl_xor(p0, o, 64); p1 += __shfl_xor(p1, o, 64); }
  if ((c & 63) == 0) { r0[c >> 6] = p0; r1[c >> 6] = p1; }
  __syncthreads();
  if (c == 0) {
    out[g * 2]     = r0[0] + r0[1] + fcb[0];
    out[g * 2 + 1] = r1[0] + r1[1] + fcb[1];
  }
}

// ---------------- host ----------------

extern "C" void kernel_launch(void* const* d_in, const int* in_sizes, int n_in,
                              void* d_out, int out_size, void* d_ws, size_t ws_size,
                              hipStream_t stream) {
  const float* x     = (const float*)d_in[0];
  const int*   eidx  = (const int*)d_in[1];
  const int*   batch = (const int*)d_in[2];
  const float* eattr = (const float*)d_in[3];
  const float* W1  = (const float*)d_in[4];
  const float* as1 = (const float*)d_in[5];
  const float* ad1 = (const float*)d_in[6];
  const float* We1 = (const float*)d_in[7];
  const float* ae1 = (const float*)d_in[8];
  const float* b1  = (const float*)d_in[9];
  const float* W2  = (const float*)d_in[10];
  const float* as2 = (const float*)d_in[11];
  const float* ad2 = (const float*)d_in[12];
  const float* We2 = (const float*)d_in[13];
  const float* ae2 = (const float*)d_in[14];
  const float* b2  = (const float*)d_in[15];
  const float* fcw = (const float*)d_in[16];
  const float* fcb = (const float*)d_in[17];

  const int N  = in_sizes[2];
  const int E  = in_sizes[1] / 2;
  const int G  = out_size / 2;
  const int E2 = E + N;
  const int nb = (N + 255) / 256;
  const int* srcI = eidx;
  const int* tgtI = eidx + E;

  char* w = (char*)d_ws;
  auto alloc = [&](size_t bytes) -> void* {
    void* p = (void*)w;
    w += (bytes + 255) & ~(size_t)255;
    return p;
  };
  int*   deg    = (int*)alloc((size_t)N * 8);        // deg + cur contiguous
  int*   cur    = deg + N;
  int*   bsum   = (int*)alloc((size_t)nb * 4);
  int*   off    = (int*)alloc((size_t)(N + 1) * 4);
  int*   csrc   = (int*)alloc((size_t)E2 * 4);
  float* eaP    = (float*)alloc((size_t)E2 * 16);
  float* a_s    = (float*)alloc((size_t)N * 32);
  float* a_d    = (float*)alloc((size_t)N * 32);
  unsigned short* h16 = (unsigned short*)alloc((size_t)N * 256);
  float* xbuf   = (float*)alloc((size_t)N * 512);
  float* M      = (float*)alloc(256);
  float* pool   = (float*)alloc((size_t)G * 512 + (size_t)G * 4);
  int*   cntg   = (int*)(pool + (size_t)G * 128);

  hipMemsetAsync(deg, 0, (size_t)N * 8, stream);
  hipMemsetAsync(pool, 0, (size_t)G * 516, stream);

  k_deg<<<(E + 255) / 256, 256, 0, stream>>>(tgtI, deg, E);
  k_bsum<<<nb, 256, 0, stream>>>(deg, bsum, N);
  k_bscan<<<1, 1024, 0, stream>>>(bsum, nb);
  k_off<<<nb, 256, 0, stream>>>(deg, bsum, off, csrc, N);
  k_filledge<<<(E + 255) / 256, 256, 0, stream>>>(srcI, tgtI, eattr, off, cur, csrc,
                                                  (float4*)eaP, E);
  k_loopattr<<<(N * 4 + 255) / 256, 256, 0, stream>>>(off, eaP, N);
  k_M<<<1, 64, 0, stream>>>(We1, ae1, We2, ae2, M);

  // layer 1 (h recomputed in aggr from x)
  k_node1<<<1024, 256, 0, stream>>>(x, W1, as1, ad1, a_s, a_d, N);
  k_aggr1<<<(N + 3) / 4, 256, 0, stream>>>(csrc, off, a_s, a_d, eaP, M, x, W1, b1, xbuf, N);

  // layer 2
  k_node2<<<1024, 256, 0, stream>>>(xbuf, W2, as2, ad2, h16, a_s, a_d, N);
  k_aggr2<<<(N + 3) / 4, 256, 0, stream>>>(csrc, off, a_s, a_d, eaP, M + 32, h16, b2, xbuf, N);

  // pool + fc
  k_pool<<<(N + PROWS - 1) / PROWS, 128, 0, stream>>>(xbuf, batch, pool, cntg, N);
  k_fc<<<G, 128, 0, stream>>>(pool, cntg, fcw, fcb, (float*)d_out, G);
}

// Round 6
// 294.609 us; speedup vs baseline: 3.0760x; 1.1267x over previous
//
#include <hip/hip_runtime.h>

#define NEG_SLOPE 0.2f

typedef __attribute__((ext_vector_type(8))) short bf16x8;
typedef __attribute__((ext_vector_type(4))) float f32x4;

__device__ __forceinline__ unsigned short f2bf(float f) {
  unsigned u = __builtin_bit_cast(unsigned, f);
  unsigned r = u + 0x7FFFu + ((u >> 16) & 1u);   // round-to-nearest-even
  return (unsigned short)(r >> 16);
}

// ---------------- graph preprocessing ----------------

__global__ void k_deg(const int* __restrict__ tgt, int* __restrict__ deg, int E) {
  int e = blockIdx.x * blockDim.x + threadIdx.x;
  if (e < E) atomicAdd(&deg[tgt[e]], 1);
}

// phase 1: per-block sums of (deg[i]+1) over 256-element chunks
__global__ __launch_bounds__(256) void k_bsum(const int* __restrict__ deg,
                                              int* __restrict__ bsum, int n) {
  __shared__ int ws[4];
  int i = blockIdx.x * 256 + threadIdx.x;
  int lane = threadIdx.x & 63, wv = threadIdx.x >> 6;
  int v = (i < n) ? deg[i] + 1 : 0;
  #pragma unroll
  for (int o = 1; o < 64; o <<= 1) v += __shfl_xor(v, o, 64);
  if (lane == 0) ws[wv] = v;
  __syncthreads();
  if (threadIdx.x == 0) bsum[blockIdx.x] = ws[0] + ws[1] + ws[2] + ws[3];
}

// phase 2: single block, exclusive scan of nb (<=1024) block sums
__global__ __launch_bounds__(1024) void k_bscan(int* __restrict__ bsum, int nb) {
  __shared__ int wsum[16];
  int tid = threadIdx.x, lane = tid & 63, wv = tid >> 6;
  int v = (tid < nb) ? bsum[tid] : 0;
  int sc = v;
  #pragma unroll
  for (int o = 1; o < 64; o <<= 1) { int t = __shfl_up(sc, o, 64); if (lane >= o) sc += t; }
  if (lane == 63) wsum[wv] = sc;
  __syncthreads();
  if (wv == 0 && lane < 16) {
    int ws = wsum[lane];
    #pragma unroll
    for (int o = 1; o < 16; o <<= 1) { int t = __shfl_up(ws, o, 64); if (lane >= o) ws += t; }
    wsum[lane] = ws;
  }
  __syncthreads();
  int excl = (wv ? wsum[wv - 1] : 0) + sc - v;
  if (tid < nb) bsum[tid] = excl;
}

// phase 3: per-block scan -> off[i+1]; fill self-loop src in last CSR slot
__global__ __launch_bounds__(256) void k_off(const int* __restrict__ deg,
                                             const int* __restrict__ bsum,
                                             int* __restrict__ off,
                                             int* __restrict__ csrc, int n) {
  __shared__ int ws[4];
  int i = blockIdx.x * 256 + threadIdx.x;
  int lane = threadIdx.x & 63, wv = threadIdx.x >> 6;
  int v = (i < n) ? deg[i] + 1 : 0;
  int sc = v;
  #pragma unroll
  for (int o = 1; o < 64; o <<= 1) { int t = __shfl_up(sc, o, 64); if (lane >= o) sc += t; }
  if (lane == 63) ws[wv] = sc;
  __syncthreads();
  int pre = bsum[blockIdx.x];
  #pragma unroll
  for (int w = 0; w < 3; ++w) if (wv > w) pre += ws[w];
  int incl = pre + sc;
  if (i < n) {
    off[i + 1] = incl;
    csrc[incl - 1] = i;          // self-loop slot
  }
  if (i == 0) off[0] = 0;
}

// scatter edges into CSR: src id + permuted edge-attr row (coalesced eattr read)
__global__ void k_filledge(const int* __restrict__ src, const int* __restrict__ tgt,
                           const float* __restrict__ eattr,
                           const int* __restrict__ off, int* __restrict__ cur,
                           int* __restrict__ csrc, float4* __restrict__ eaP, int E) {
  int e = blockIdx.x * blockDim.x + threadIdx.x;
  if (e >= E) return;
  int t = tgt[e];
  int pos = off[t] + atomicAdd(&cur[t], 1);
  csrc[pos] = src[e];
  eaP[pos] = reinterpret_cast<const float4*>(eattr)[e];
}

// self-slot attr = mean of the node's incoming eaP rows (0 if none)
__global__ void k_loopattr(const int* __restrict__ off, float* __restrict__ eaP, int N) {
  int idx = blockIdx.x * blockDim.x + threadIdx.x;
  int n = idx >> 2, c = idx & 3;
  if (n >= N) return;
  int beg = off[n], end = off[n + 1] - 1;  // exclude self slot
  float s = 0.f;
  for (int i = beg; i < end; ++i) s += eaP[(size_t)i * 4 + c];
  eaP[(size_t)end * 4 + c] = s / (float)max(end - beg, 1);
}

// M[layer][k][h] = sum_c We[k,h*16+c] * ae[h*16+c]; also W16t[c][k] = bf16(W2[k][c])
__global__ __launch_bounds__(256) void k_M(const float* __restrict__ We1, const float* __restrict__ ae1,
                    const float* __restrict__ We2, const float* __restrict__ ae2,
                    const float* __restrict__ W2, unsigned short* __restrict__ W16t,
                    float* __restrict__ M) {
  int tid = threadIdx.x;
  if (tid < 64) {
    int layer = tid >> 5, kh = tid & 31;
    int k = kh >> 3, h = kh & 7;
    const float* We = layer ? We2 : We1;
    const float* ae = layer ? ae2 : ae1;
    float acc = 0.f;
    for (int c = 0; c < 16; ++c) acc += We[k * 128 + h * 16 + c] * ae[h * 16 + c];
    M[layer * 32 + k * 8 + h] = acc;
  }
  for (int i = tid; i < 16384; i += 256) {
    int c = i >> 7, k = i & 127;
    W16t[c * 128 + k] = f2bf(W2[k * 128 + c]);
  }
}

// ---------------- layer kernels ----------------

// layer-1 node terms only (a_s, a_d) — h recomputed on the fly in k_aggr1
__global__ __launch_bounds__(256) void k_node1(const float* __restrict__ x,
    const float* __restrict__ W, const float* __restrict__ as_, const float* __restrict__ ad_,
    float* __restrict__ a_s, float* __restrict__ a_d, int N) {
  __shared__ float Wl[512];
  __shared__ float asl[128], adl[128];
  int tid = threadIdx.x;
  for (int i = tid; i < 512; i += 256) Wl[i] = W[i];
  if (tid < 128) { asl[tid] = as_[tid]; adl[tid] = ad_[tid]; }
  __syncthreads();
  int c = tid & 127, half = tid >> 7;
  for (int n0 = blockIdx.x * 2; n0 < N; n0 += gridDim.x * 2) {
    int n = n0 + half;
    if (n < N) {
      float4 xr = *reinterpret_cast<const float4*>(x + (size_t)n * 4);
      float hv = xr.x * Wl[c] + xr.y * Wl[128 + c] + xr.z * Wl[256 + c] + xr.w * Wl[384 + c];
      float ps = hv * asl[c], pd = hv * adl[c];
      for (int o = 1; o < 16; o <<= 1) { ps += __shfl_xor(ps, o, 64); pd += __shfl_xor(pd, o, 64); }
      if ((c & 15) == 0) { a_s[n * 8 + (c >> 4)] = ps; a_d[n * 8 + (c >> 4)] = pd; }
    }
  }
}

// layer-2 linear via MFMA: h2 = x16 @ W2 (bf16 in, f32 acc). One wave per 16-node
// tile; no LDS. A: lane&15=row, k=(lane>>4)*8+j. B from W16t[c][k]: lane&15=col.
// D: col=lane&15, row=(lane>>4)*4+reg. col-tile t == head t (16 ch).
__global__ __launch_bounds__(256) void k_node2(const unsigned short* __restrict__ x16,
    const unsigned short* __restrict__ W16t,
    const float* __restrict__ as_, const float* __restrict__ ad_,
    unsigned short* __restrict__ h16, float* __restrict__ a_s, float* __restrict__ a_d, int N) {
  int wv = threadIdx.x >> 6, lane = threadIdx.x & 63;
  int n0 = (blockIdx.x * 4 + wv) * 16;
  if (n0 >= N) return;
  int r = lane & 15, g = lane >> 4;
  bf16x8 a[4];
  #pragma unroll
  for (int kb = 0; kb < 4; ++kb)
    a[kb] = *reinterpret_cast<const bf16x8*>(x16 + (size_t)(n0 + r) * 128 + kb * 32 + g * 8);
  #pragma unroll
  for (int t = 0; t < 8; ++t) {
    f32x4 acc = {0.f, 0.f, 0.f, 0.f};
    #pragma unroll
    for (int kb = 0; kb < 4; ++kb) {
      bf16x8 b = *reinterpret_cast<const bf16x8*>(W16t + (size_t)(t * 16 + r) * 128 + kb * 32 + g * 8);
      acc = __builtin_amdgcn_mfma_f32_16x16x32_bf16(a[kb], b, acc, 0, 0, 0);
    }
    float asv = as_[t * 16 + r], adv = ad_[t * 16 + r];
    float ps[4], pd[4];
    #pragma unroll
    for (int j = 0; j < 4; ++j) { ps[j] = acc[j] * asv; pd[j] = acc[j] * adv; }
    #pragma unroll
    for (int o = 1; o < 16; o <<= 1) {
      #pragma unroll
      for (int j = 0; j < 4; ++j) {
        ps[j] += __shfl_xor(ps[j], o, 64);
        pd[j] += __shfl_xor(pd[j], o, 64);
      }
    }
    #pragma unroll
    for (int j = 0; j < 4; ++j) {
      int row = n0 + g * 4 + j;
      if (row < N) {
        h16[(size_t)row * 128 + t * 16 + r] = f2bf(acc[j]);
        if (r == 0) { a_s[(size_t)row * 8 + t] = ps[j]; a_d[(size_t)row * 8 + t] = pd[j]; }
      }
    }
  }
}

// layer-1 aggregate: h[src] recomputed from x[src] (16 B, L2-resident). Plain exp.
// Output written as packed bf16 (layer-2 input).
__global__ __launch_bounds__(256) void k_aggr1(const int* __restrict__ csrc,
    const int* __restrict__ off, const float* __restrict__ a_s, const float* __restrict__ a_d,
    const float* __restrict__ eaP, const float* __restrict__ M,
    const float* __restrict__ x, const float* __restrict__ W,
    const float* __restrict__ bias, unsigned short* __restrict__ x16, int N) {
  int wid = (blockIdx.x * blockDim.x + threadIdx.x) >> 6;
  if (wid >= N) return;
  int lane = threadIdx.x & 63;
  int head = lane >> 3;
  float2 w0 = *reinterpret_cast<const float2*>(W + lane * 2);
  float2 w1 = *reinterpret_cast<const float2*>(W + 128 + lane * 2);
  float2 w2 = *reinterpret_cast<const float2*>(W + 256 + lane * 2);
  float2 w3 = *reinterpret_cast<const float2*>(W + 384 + lane * 2);
  float M0 = M[head], M1 = M[8 + head], M2 = M[16 + head], M3 = M[24 + head];
  float ad = a_d[(size_t)wid * 8 + head];
  int beg = off[wid], end = off[wid + 1];
  float sum = 0.f, acc0 = 0.f, acc1 = 0.f;
  int i = beg;
  for (; i + 4 <= end; i += 4) {
    int ib = __builtin_amdgcn_readfirstlane(i);
    int s0 = __builtin_amdgcn_readfirstlane(csrc[ib]);
    int s1 = __builtin_amdgcn_readfirstlane(csrc[ib + 1]);
    int s2 = __builtin_amdgcn_readfirstlane(csrc[ib + 2]);
    int s3 = __builtin_amdgcn_readfirstlane(csrc[ib + 3]);
    float4 e0 = *reinterpret_cast<const float4*>(eaP + (size_t)ib * 4);
    float4 e1 = *reinterpret_cast<const float4*>(eaP + (size_t)(ib + 1) * 4);
    float4 e2 = *reinterpret_cast<const float4*>(eaP + (size_t)(ib + 2) * 4);
    float4 e3 = *reinterpret_cast<const float4*>(eaP + (size_t)(ib + 3) * 4);
    float4 x0 = *reinterpret_cast<const float4*>(x + (size_t)s0 * 4);
    float4 x1 = *reinterpret_cast<const float4*>(x + (size_t)s1 * 4);
    float4 x2 = *reinterpret_cast<const float4*>(x + (size_t)s2 * 4);
    float4 x3 = *reinterpret_cast<const float4*>(x + (size_t)s3 * 4);
    float v0 = a_s[(size_t)s0 * 8 + head], v1 = a_s[(size_t)s1 * 8 + head];
    float v2 = a_s[(size_t)s2 * 8 + head], v3 = a_s[(size_t)s3 * 8 + head];
    float a0 = v0 + ad + e0.x * M0 + e0.y * M1 + e0.z * M2 + e0.w * M3;
    float a1 = v1 + ad + e1.x * M0 + e1.y * M1 + e1.z * M2 + e1.w * M3;
    float a2 = v2 + ad + e2.x * M0 + e2.y * M1 + e2.z * M2 + e2.w * M3;
    float a3 = v3 + ad + e3.x * M0 + e3.y * M1 + e3.z * M2 + e3.w * M3;
    a0 = a0 > 0.f ? a0 : NEG_SLOPE * a0;
    a1 = a1 > 0.f ? a1 : NEG_SLOPE * a1;
    a2 = a2 > 0.f ? a2 : NEG_SLOPE * a2;
    a3 = a3 > 0.f ? a3 : NEG_SLOPE * a3;
    float p0 = __expf(a0), p1 = __expf(a1), p2 = __expf(a2), p3 = __expf(a3);
    sum += (p0 + p1) + (p2 + p3);
    float h0x = x0.x * w0.x + x0.y * w1.x + x0.z * w2.x + x0.w * w3.x;
    float h0y = x0.x * w0.y + x0.y * w1.y + x0.z * w2.y + x0.w * w3.y;
    float h1x = x1.x * w0.x + x1.y * w1.x + x1.z * w2.x + x1.w * w3.x;
    float h1y = x1.x * w0.y + x1.y * w1.y + x1.z * w2.y + x1.w * w3.y;
    float h2x = x2.x * w0.x + x2.y * w1.x + x2.z * w2.x + x2.w * w3.x;
    float h2y = x2.x * w0.y + x2.y * w1.y + x2.z * w2.y + x2.w * w3.y;
    float h3x = x3.x * w0.x + x3.y * w1.x + x3.z * w2.x + x3.w * w3.x;
    float h3y = x3.x * w0.y + x3.y * w1.y + x3.z * w2.y + x3.w * w3.y;
    acc0 += (p0 * h0x + p1 * h1x) + (p2 * h2x + p3 * h3x);
    acc1 += (p0 * h0y + p1 * h1y) + (p2 * h2y + p3 * h3y);
  }
  for (; i < end; ++i) {
    int ib = __builtin_amdgcn_readfirstlane(i);
    int s0 = __builtin_amdgcn_readfirstlane(csrc[ib]);
    float4 e0 = *reinterpret_cast<const float4*>(eaP + (size_t)ib * 4);
    float4 x0 = *reinterpret_cast<const float4*>(x + (size_t)s0 * 4);
    float a0 = a_s[(size_t)s0 * 8 + head] + ad + e0.x * M0 + e0.y * M1 + e0.z * M2 + e0.w * M3;
    a0 = a0 > 0.f ? a0 : NEG_SLOPE * a0;
    float p0 = __expf(a0);
    sum += p0;
    acc0 += p0 * (x0.x * w0.x + x0.y * w1.x + x0.z * w2.x + x0.w * w3.x);
    acc1 += p0 * (x0.x * w0.y + x0.y * w1.y + x0.z * w2.y + x0.w * w3.y);
  }
  float inv = 1.f / (sum + 1e-16f);
  float o0 = fmaxf(acc0 * inv + bias[lane * 2], 0.f);
  float o1 = fmaxf(acc1 * inv + bias[lane * 2 + 1], 0.f);
  unsigned pk = ((unsigned)f2bf(o1) << 16) | (unsigned)f2bf(o0);
  *reinterpret_cast<unsigned*>(x16 + (size_t)wid * 128 + lane * 2) = pk;
}

// layer-2 aggregate: gathers 256 B bf16 h rows; unroll 8, plain exp
__global__ __launch_bounds__(256) void k_aggr2(const int* __restrict__ csrc,
    const int* __restrict__ off, const float* __restrict__ a_s, const float* __restrict__ a_d,
    const float* __restrict__ eaP, const float* __restrict__ M,
    const unsigned short* __restrict__ h16, const float* __restrict__ bias,
    float* __restrict__ xout, int N) {
  int wid = (blockIdx.x * blockDim.x + threadIdx.x) >> 6;
  if (wid >= N) return;
  int lane = threadIdx.x & 63;
  int head = lane >> 3;
  float M0 = M[head], M1 = M[8 + head], M2 = M[16 + head], M3 = M[24 + head];
  float ad = a_d[(size_t)wid * 8 + head];
  int beg = off[wid], end = off[wid + 1];
  float sum = 0.f, acc0 = 0.f, acc1 = 0.f;
  int i = beg;
  for (; i + 8 <= end; i += 8) {
    int ib = __builtin_amdgcn_readfirstlane(i);
    int s[8]; float4 e[8]; unsigned hu[8]; float v[8];
    #pragma unroll
    for (int j = 0; j < 8; ++j) s[j] = csrc[ib + j];
    #pragma unroll
    for (int j = 0; j < 8; ++j) e[j] = *reinterpret_cast<const float4*>(eaP + (size_t)(ib + j) * 4);
    #pragma unroll
    for (int j = 0; j < 8; ++j)
      hu[j] = *reinterpret_cast<const unsigned*>(h16 + (size_t)s[j] * 128 + lane * 2);
    #pragma unroll
    for (int j = 0; j < 8; ++j) v[j] = a_s[(size_t)s[j] * 8 + head];
    #pragma unroll
    for (int j = 0; j < 8; ++j) {
      float a = v[j] + ad + e[j].x * M0 + e[j].y * M1 + e[j].z * M2 + e[j].w * M3;
      a = a > 0.f ? a : NEG_SLOPE * a;
      float p = __expf(a);
      sum += p;
      acc0 += p * __builtin_bit_cast(float, hu[j] << 16);
      acc1 += p * __builtin_bit_cast(float, hu[j] & 0xFFFF0000u);
    }
  }
  for (; i < end; ++i) {
    int ib = __builtin_amdgcn_readfirstlane(i);
    int s0 = csrc[ib];
    float4 e0 = *reinterpret_cast<const float4*>(eaP + (size_t)ib * 4);
    unsigned hu = *reinterpret_cast<const unsigned*>(h16 + (size_t)s0 * 128 + lane * 2);
    float a0 = a_s[(size_t)s0 * 8 + head] + ad + e0.x * M0 + e0.y * M1 + e0.z * M2 + e0.w * M3;
    a0 = a0 > 0.f ? a0 : NEG_SLOPE * a0;
    float p0 = __expf(a0);
    sum += p0;
    acc0 += p0 * __builtin_bit_cast(float, hu << 16);
    acc1 += p0 * __builtin_bit_cast(float, hu & 0xFFFF0000u);
  }
  float inv = 1.f / (sum + 1e-16f);
  float o0 = fmaxf(acc0 * inv + bias[lane * 2], 0.f);
  float o1 = fmaxf(acc1 * inv + bias[lane * 2 + 1], 0.f);
  *reinterpret_cast<float2*>(xout + (size_t)wid * 128 + lane * 2) = make_float2(o0, o1);
}

// ---------------- pooling + FC ----------------

#define PROWS 128
__global__ __launch_bounds__(128) void k_pool(const float* __restrict__ x,
    const int* __restrict__ batch, float* __restrict__ pool, int* __restrict__ cntg, int N) {
  int c = threadIdx.x;
  int n0 = blockIdx.x * PROWS;
  if (n0 >= N) return;
  int nend = min(n0 + PROWS, N);
  float acc = 0.f; int cnt = 0; int g = batch[n0];
  for (int n = n0; n < nend; ++n) {
    int bn = batch[n];
    if (bn != g) {
      atomicAdd(&pool[(size_t)g * 128 + c], acc);
      if (c == 0) atomicAdd(&cntg[g], cnt);
      acc = 0.f; cnt = 0; g = bn;
    }
    acc += x[(size_t)n * 128 + c];
    cnt++;
  }
  atomicAdd(&pool[(size_t)g * 128 + c], acc);
  if (c == 0) atomicAdd(&cntg[g], cnt);
}

__global__ __launch_bounds__(128) void k_fc(const float* __restrict__ pool,
    const int* __restrict__ cntg, const float* __restrict__ fcw,
    const float* __restrict__ fcb, float* __restrict__ out, int G) {
  int g = blockIdx.x, c = threadIdx.x;
  __shared__ float r0[2], r1[2];
  float inv = 1.f / (float)max(cntg[g], 1);
  float v = pool[(size_t)g * 128 + c] * inv;
  float p0 = v * fcw[c * 2], p1 = v * fcw[c * 2 + 1];
  for (int o = 1; o < 64; o <<= 1) { p0 += __shfl_xor(p0, o, 64); p1 += __shfl_xor(p1, o, 64); }
  if ((c & 63) == 0) { r0[c >> 6] = p0; r1[c >> 6] = p1; }
  __syncthreads();
  if (c == 0) {
    out[g * 2]     = r0[0] + r0[1] + fcb[0];
    out[g * 2 + 1] = r1[0] + r1[1] + fcb[1];
  }
}

// ---------------- host ----------------

extern "C" void kernel_launch(void* const* d_in, const int* in_sizes, int n_in,
                              void* d_out, int out_size, void* d_ws, size_t ws_size,
                              hipStream_t stream) {
  const float* x     = (const float*)d_in[0];
  const int*   eidx  = (const int*)d_in[1];
  const int*   batch = (const int*)d_in[2];
  const float* eattr = (const float*)d_in[3];
  const float* W1  = (const float*)d_in[4];
  const float* as1 = (const float*)d_in[5];
  const float* ad1 = (const float*)d_in[6];
  const float* We1 = (const float*)d_in[7];
  const float* ae1 = (const float*)d_in[8];
  const float* b1  = (const float*)d_in[9];
  const float* W2  = (const float*)d_in[10];
  const float* as2 = (const float*)d_in[11];
  const float* ad2 = (const float*)d_in[12];
  const float* We2 = (const float*)d_in[13];
  const float* ae2 = (const float*)d_in[14];
  const float* b2  = (const float*)d_in[15];
  const float* fcw = (const float*)d_in[16];
  const float* fcb = (const float*)d_in[17];

  const int N  = in_sizes[2];
  const int E  = in_sizes[1] / 2;
  const int G  = out_size / 2;
  const int E2 = E + N;
  const int nb = (N + 255) / 256;
  const int* srcI = eidx;
  const int* tgtI = eidx + E;

  char* w = (char*)d_ws;
  auto alloc = [&](size_t bytes) -> void* {
    void* p = (void*)w;
    w += (bytes + 255) & ~(size_t)255;
    return p;
  };
  int*   deg    = (int*)alloc((size_t)N * 8);        // deg + cur contiguous
  int*   cur    = deg + N;
  int*   bsum   = (int*)alloc((size_t)nb * 4);
  int*   off    = (int*)alloc((size_t)(N + 1) * 4);
  int*   csrc   = (int*)alloc((size_t)E2 * 4);
  float* eaP    = (float*)alloc((size_t)E2 * 16);
  float* a_s    = (float*)alloc((size_t)N * 32);
  float* a_d    = (float*)alloc((size_t)N * 32);
  unsigned short* x16 = (unsigned short*)alloc((size_t)N * 256);
  unsigned short* h16 = (unsigned short*)alloc((size_t)N * 256);
  unsigned short* W16t = (unsigned short*)alloc(128 * 128 * 2);
  float* xbuf   = (float*)alloc((size_t)N * 512);
  float* M      = (float*)alloc(256);
  float* pool   = (float*)alloc((size_t)G * 512 + (size_t)G * 4);
  int*   cntg   = (int*)(pool + (size_t)G * 128);

  hipMemsetAsync(deg, 0, (size_t)N * 8, stream);
  hipMemsetAsync(pool, 0, (size_t)G * 516, stream);

  k_deg<<<(E + 255) / 256, 256, 0, stream>>>(tgtI, deg, E);
  k_bsum<<<nb, 256, 0, stream>>>(deg, bsum, N);
  k_bscan<<<1, 1024, 0, stream>>>(bsum, nb);
  k_off<<<nb, 256, 0, stream>>>(deg, bsum, off, csrc, N);
  k_filledge<<<(E + 255) / 256, 256, 0, stream>>>(srcI, tgtI, eattr, off, cur, csrc,
                                                  (float4*)eaP, E);
  k_loopattr<<<(N * 4 + 255) / 256, 256, 0, stream>>>(off, eaP, N);
  k_M<<<1, 256, 0, stream>>>(We1, ae1, We2, ae2, W2, W16t, M);

  // layer 1 (h recomputed in aggr from x); output packed bf16
  k_node1<<<1024, 256, 0, stream>>>(x, W1, as1, ad1, a_s, a_d, N);
  k_aggr1<<<(N + 3) / 4, 256, 0, stream>>>(csrc, off, a_s, a_d, eaP, M, x, W1, b1, x16, N);

  // layer 2 (MFMA linear)
  k_node2<<<(N + 63) / 64, 256, 0, stream>>>(x16, W16t, as2, ad2, h16, a_s, a_d, N);
  k_aggr2<<<(N + 3) / 4, 256, 0, stream>>>(csrc, off, a_s, a_d, eaP, M + 32, h16, b2, xbuf, N);

  // pool + fc
  k_pool<<<(N + PROWS - 1) / PROWS, 128, 0, stream>>>(xbuf, batch, pool, cntg, N);
  k_fc<<<G, 128, 0, stream>>>(pool, cntg, fcw, fcb, (float*)d_out, G);
}

// Round 7
// 283.510 us; speedup vs baseline: 3.1965x; 1.0392x over previous
//
#include <hip/hip_runtime.h>

#define NEG_SLOPE 0.2f

typedef __attribute__((ext_vector_type(8))) short bf16x8;
typedef __attribute__((ext_vector_type(4))) float f32x4;

__device__ __forceinline__ unsigned short f2bf(float f) {
  unsigned u = __builtin_bit_cast(unsigned, f);
  unsigned r = u + 0x7FFFu + ((u >> 16) & 1u);   // round-to-nearest-even
  return (unsigned short)(r >> 16);
}

// CSR slot: 32 B = {float ea[4]; int src; pad[3]}  (single-line scatter target)

// ---------------- graph preprocessing ----------------

__global__ void k_deg(const int* __restrict__ tgt, int* __restrict__ deg, int E) {
  int e = blockIdx.x * blockDim.x + threadIdx.x;
  if (e < E) atomicAdd(&deg[tgt[e]], 1);
}

// phase 1: per-block sums of (deg[i]+1) over 256-element chunks
__global__ __launch_bounds__(256) void k_bsum(const int* __restrict__ deg,
                                              int* __restrict__ bsum, int n) {
  __shared__ int ws[4];
  int i = blockIdx.x * 256 + threadIdx.x;
  int lane = threadIdx.x & 63, wv = threadIdx.x >> 6;
  int v = (i < n) ? deg[i] + 1 : 0;
  #pragma unroll
  for (int o = 1; o < 64; o <<= 1) v += __shfl_xor(v, o, 64);
  if (lane == 0) ws[wv] = v;
  __syncthreads();
  if (threadIdx.x == 0) bsum[blockIdx.x] = ws[0] + ws[1] + ws[2] + ws[3];
}

// phase 2: single block, exclusive scan of nb (<=1024) block sums
__global__ __launch_bounds__(1024) void k_bscan(int* __restrict__ bsum, int nb) {
  __shared__ int wsum[16];
  int tid = threadIdx.x, lane = tid & 63, wv = tid >> 6;
  int v = (tid < nb) ? bsum[tid] : 0;
  int sc = v;
  #pragma unroll
  for (int o = 1; o < 64; o <<= 1) { int t = __shfl_up(sc, o, 64); if (lane >= o) sc += t; }
  if (lane == 63) wsum[wv] = sc;
  __syncthreads();
  if (wv == 0 && lane < 16) {
    int ws = wsum[lane];
    #pragma unroll
    for (int o = 1; o < 16; o <<= 1) { int t = __shfl_up(ws, o, 64); if (lane >= o) ws += t; }
    wsum[lane] = ws;
  }
  __syncthreads();
  int excl = (wv ? wsum[wv - 1] : 0) + sc - v;
  if (tid < nb) bsum[tid] = excl;
}

// phase 3: per-block scan -> off[i+1]; self-loop src into last CSR slot
__global__ __launch_bounds__(256) void k_off(const int* __restrict__ deg,
                                             const int* __restrict__ bsum,
                                             int* __restrict__ off,
                                             float* __restrict__ slot, int n) {
  __shared__ int ws[4];
  int i = blockIdx.x * 256 + threadIdx.x;
  int lane = threadIdx.x & 63, wv = threadIdx.x >> 6;
  int v = (i < n) ? deg[i] + 1 : 0;
  int sc = v;
  #pragma unroll
  for (int o = 1; o < 64; o <<= 1) { int t = __shfl_up(sc, o, 64); if (lane >= o) sc += t; }
  if (lane == 63) ws[wv] = sc;
  __syncthreads();
  int pre = bsum[blockIdx.x];
  #pragma unroll
  for (int w = 0; w < 3; ++w) if (wv > w) pre += ws[w];
  int incl = pre + sc;
  if (i < n) {
    off[i + 1] = incl;
    reinterpret_cast<int*>(slot)[(size_t)(incl - 1) * 8 + 4] = i;  // self-loop src
  }
  if (i == 0) off[0] = 0;
}

// scatter edges into CSR slots: one aligned 32B chunk per edge
__global__ void k_filledge(const int* __restrict__ src, const int* __restrict__ tgt,
                           const float* __restrict__ eattr,
                           const int* __restrict__ off, int* __restrict__ cur,
                           float* __restrict__ slot, int E) {
  int e = blockIdx.x * blockDim.x + threadIdx.x;
  if (e >= E) return;
  int t = tgt[e];
  int pos = off[t] + atomicAdd(&cur[t], 1);
  reinterpret_cast<float4*>(slot)[(size_t)pos * 2] = reinterpret_cast<const float4*>(eattr)[e];
  reinterpret_cast<int*>(slot)[(size_t)pos * 8 + 4] = src[e];
}

// self-slot attr = mean of the node's incoming slot.ea rows (0 if none)
__global__ void k_loopattr(const int* __restrict__ off, float* __restrict__ slot, int N) {
  int idx = blockIdx.x * blockDim.x + threadIdx.x;
  int n = idx >> 2, c = idx & 3;
  if (n >= N) return;
  int beg = off[n], endS = off[n + 1] - 1;  // exclude self slot
  float s = 0.f;
  for (int i = beg; i < endS; ++i) s += slot[(size_t)i * 8 + c];
  slot[(size_t)endS * 8 + c] = s / (float)max(endS - beg, 1);
}

// M[layer][k][h]; W16t[c][k]=bf16(W2[k][c]); vab[kind][d][h]=sum_c W1[d][h*16+c]*att[h*16+c]
__global__ __launch_bounds__(256) void k_M(const float* __restrict__ We1, const float* __restrict__ ae1,
                    const float* __restrict__ We2, const float* __restrict__ ae2,
                    const float* __restrict__ W2, const float* __restrict__ W1,
                    const float* __restrict__ as1, const float* __restrict__ ad1,
                    unsigned short* __restrict__ W16t,
                    float* __restrict__ M, float* __restrict__ vab) {
  int tid = threadIdx.x;
  if (tid < 64) {
    int layer = tid >> 5, kh = tid & 31;
    int k = kh >> 3, h = kh & 7;
    const float* We = layer ? We2 : We1;
    const float* ae = layer ? ae2 : ae1;
    float acc = 0.f;
    for (int c = 0; c < 16; ++c) acc += We[k * 128 + h * 16 + c] * ae[h * 16 + c];
    M[layer * 32 + k * 8 + h] = acc;
  } else if (tid >= 128 && tid < 192) {
    int i = tid - 128;
    int kind = i >> 5, rem = i & 31;
    int d = rem >> 3, h = rem & 7;
    const float* att = kind ? ad1 : as1;
    float acc = 0.f;
    for (int c = 0; c < 16; ++c) acc += W1[d * 128 + h * 16 + c] * att[h * 16 + c];
    vab[kind * 32 + d * 8 + h] = acc;
  }
  for (int i = tid; i < 16384; i += 256) {
    int c = i >> 7, k = i & 127;
    W16t[c * 128 + k] = f2bf(W2[k * 128 + c]);
  }
}

// ---------------- layer kernels ----------------

// layer-1 node terms via low-rank tables: a_s[n][h] = x[n].va[:,h]
__global__ __launch_bounds__(256) void k_node1(const float* __restrict__ x,
    const float* __restrict__ vab, float* __restrict__ a_s, float* __restrict__ a_d, int N) {
  int idx = blockIdx.x * blockDim.x + threadIdx.x;
  int n = idx >> 3, h = idx & 7;
  if (n >= N) return;
  float4 xr = *reinterpret_cast<const float4*>(x + (size_t)n * 4);
  a_s[idx] = xr.x * vab[h] + xr.y * vab[8 + h] + xr.z * vab[16 + h] + xr.w * vab[24 + h];
  a_d[idx] = xr.x * vab[32 + h] + xr.y * vab[40 + h] + xr.z * vab[48 + h] + xr.w * vab[56 + h];
}

// layer-2 linear via MFMA: h2 = x16 @ W2 (bf16 in, f32 acc). One wave per 16-node tile.
__global__ __launch_bounds__(256) void k_node2(const unsigned short* __restrict__ x16,
    const unsigned short* __restrict__ W16t,
    const float* __restrict__ as_, const float* __restrict__ ad_,
    unsigned short* __restrict__ h16, float* __restrict__ a_s, float* __restrict__ a_d, int N) {
  int wv = threadIdx.x >> 6, lane = threadIdx.x & 63;
  int n0 = (blockIdx.x * 4 + wv) * 16;
  if (n0 >= N) return;
  int r = lane & 15, g = lane >> 4;
  bf16x8 a[4];
  #pragma unroll
  for (int kb = 0; kb < 4; ++kb)
    a[kb] = *reinterpret_cast<const bf16x8*>(x16 + (size_t)(n0 + r) * 128 + kb * 32 + g * 8);
  #pragma unroll
  for (int t = 0; t < 8; ++t) {
    f32x4 acc = {0.f, 0.f, 0.f, 0.f};
    #pragma unroll
    for (int kb = 0; kb < 4; ++kb) {
      bf16x8 b = *reinterpret_cast<const bf16x8*>(W16t + (size_t)(t * 16 + r) * 128 + kb * 32 + g * 8);
      acc = __builtin_amdgcn_mfma_f32_16x16x32_bf16(a[kb], b, acc, 0, 0, 0);
    }
    float asv = as_[t * 16 + r], adv = ad_[t * 16 + r];
    float ps[4], pd[4];
    #pragma unroll
    for (int j = 0; j < 4; ++j) { ps[j] = acc[j] * asv; pd[j] = acc[j] * adv; }
    #pragma unroll
    for (int o = 1; o < 16; o <<= 1) {
      #pragma unroll
      for (int j = 0; j < 4; ++j) {
        ps[j] += __shfl_xor(ps[j], o, 64);
        pd[j] += __shfl_xor(pd[j], o, 64);
      }
    }
    #pragma unroll
    for (int j = 0; j < 4; ++j) {
      int row = n0 + g * 4 + j;
      if (row < N) {
        h16[(size_t)row * 128 + t * 16 + r] = f2bf(acc[j]);
        if (r == 0) { a_s[(size_t)row * 8 + t] = ps[j]; a_d[(size_t)row * 8 + t] = pd[j]; }
      }
    }
  }
}

// layer-1 aggregate via LINEARITY: out = ((sum_e p_e x[src_e]) @ W1)/S + b.
// lane = (j<<5)|(h<<2)|d : edge-pair j, head h, x-dim d. 1 FMA/edge/lane.
__global__ __launch_bounds__(256) void k_aggr1(const float* __restrict__ slot,
    const int* __restrict__ off, const float* __restrict__ a_s, const float* __restrict__ a_d,
    const float* __restrict__ M, const float* __restrict__ x,
    const float* __restrict__ W, const float* __restrict__ bias,
    unsigned short* __restrict__ x16, int N) {
  int wid = (blockIdx.x * blockDim.x + threadIdx.x) >> 6;
  if (wid >= N) return;
  int lane = threadIdx.x & 63;
  int j = lane >> 5, h = (lane >> 2) & 7, d = lane & 3;
  float M0 = M[h], M1 = M[8 + h], M2 = M[16 + h], M3 = M[24 + h];
  float adv = a_d[(size_t)wid * 8 + h];
  int beg = off[wid], end = off[wid + 1];
  float S = 0.f, X = 0.f;
  int i = beg;
  for (; i + 2 <= end; i += 2) {
    int ib = __builtin_amdgcn_readfirstlane(i) + j;
    float4 ea = *reinterpret_cast<const float4*>(slot + (size_t)ib * 8);
    int s = reinterpret_cast<const int*>(slot)[(size_t)ib * 8 + 4];
    float asv = a_s[(size_t)s * 8 + h];
    float xv = x[(size_t)s * 4 + d];
    float a = asv + adv + ea.x * M0 + ea.y * M1 + ea.z * M2 + ea.w * M3;
    a = a > 0.f ? a : NEG_SLOPE * a;
    float p = __expf(a);
    S += p; X += p * xv;
  }
  if (i < end) {
    int ib = __builtin_amdgcn_readfirstlane(i);
    float4 ea = *reinterpret_cast<const float4*>(slot + (size_t)ib * 8);
    int s = reinterpret_cast<const int*>(slot)[(size_t)ib * 8 + 4];
    float asv = a_s[(size_t)s * 8 + h];
    float xv = x[(size_t)s * 4 + d];
    float a = asv + adv + ea.x * M0 + ea.y * M1 + ea.z * M2 + ea.w * M3;
    a = a > 0.f ? a : NEG_SLOPE * a;
    float p = __expf(a);
    if (j == 0) { S += p; X += p * xv; }
  }
  X += __shfl_xor(X, 32, 64);
  S += __shfl_xor(S, 32, 64);
  // redistribute: lane (head H=lane>>3) needs X[H][0..3], S[H] (held by lanes H*4+d)
  int H4 = (lane >> 3) << 2;
  float x0 = __shfl(X, H4, 64),     x1 = __shfl(X, H4 + 1, 64);
  float x2 = __shfl(X, H4 + 2, 64), x3 = __shfl(X, H4 + 3, 64);
  float Sh = __shfl(S, H4, 64);
  float inv = 1.f / (Sh + 1e-16f);
  int c0 = lane * 2, c1 = lane * 2 + 1;
  float o0 = (x0 * W[c0] + x1 * W[128 + c0] + x2 * W[256 + c0] + x3 * W[384 + c0]) * inv + bias[c0];
  float o1 = (x0 * W[c1] + x1 * W[128 + c1] + x2 * W[256 + c1] + x3 * W[384 + c1]) * inv + bias[c1];
  o0 = fmaxf(o0, 0.f); o1 = fmaxf(o1, 0.f);
  unsigned pk = ((unsigned)f2bf(o1) << 16) | (unsigned)f2bf(o0);
  *reinterpret_cast<unsigned*>(x16 + (size_t)wid * 128 + lane * 2) = pk;
}

// layer-2 aggregate: alpha computed once per (edge,head) on lane (j<<3)|h,
// broadcast via shuffles; per-lane bf16 h-row gather as before.
__global__ __launch_bounds__(256) void k_aggr2(const float* __restrict__ slot,
    const int* __restrict__ off, const float* __restrict__ a_s, const float* __restrict__ a_d,
    const float* __restrict__ M, const unsigned short* __restrict__ h16,
    const float* __restrict__ bias, float* __restrict__ xout, int N) {
  int wid = (blockIdx.x * blockDim.x + threadIdx.x) >> 6;
  if (wid >= N) return;
  int lane = threadIdx.x & 63;
  int H = lane >> 3;                   // consumer head
  int ja = lane >> 3, ha = lane & 7;   // alpha role: edge ja, head ha
  float Ma0 = M[ha], Ma1 = M[8 + ha], Ma2 = M[16 + ha], Ma3 = M[24 + ha];
  float MH0 = M[H],  MH1 = M[8 + H],  MH2 = M[16 + H],  MH3 = M[24 + H];
  float adA = a_d[(size_t)wid * 8 + ha];
  float adH = a_d[(size_t)wid * 8 + H];
  int beg = off[wid], end = off[wid + 1];
  float sum = 0.f, acc0 = 0.f, acc1 = 0.f;
  int i = beg;
  for (; i + 8 <= end; i += 8) {
    int ib = __builtin_amdgcn_readfirstlane(i);
    float4 ea = *reinterpret_cast<const float4*>(slot + (size_t)(ib + ja) * 8);
    int sA = reinterpret_cast<const int*>(slot)[(size_t)(ib + ja) * 8 + 4];
    float asv = a_s[(size_t)sA * 8 + ha];
    float a = asv + adA + ea.x * Ma0 + ea.y * Ma1 + ea.z * Ma2 + ea.w * Ma3;
    a = a > 0.f ? a : NEG_SLOPE * a;
    float p = __expf(a);
    #pragma unroll
    for (int jj = 0; jj < 8; ++jj) {
      int sj = __shfl(sA, jj * 8, 64);
      float pj = __shfl(p, jj * 8 + H, 64);
      unsigned hu = *reinterpret_cast<const unsigned*>(h16 + (size_t)sj * 128 + lane * 2);
      sum += pj;
      acc0 += pj * __builtin_bit_cast(float, hu << 16);
      acc1 += pj * __builtin_bit_cast(float, hu & 0xFFFF0000u);
    }
  }
  for (; i < end; ++i) {
    int ib = __builtin_amdgcn_readfirstlane(i);
    float4 e0 = *reinterpret_cast<const float4*>(slot + (size_t)ib * 8);
    int s0 = reinterpret_cast<const int*>(slot)[(size_t)ib * 8 + 4];
    unsigned hu = *reinterpret_cast<const unsigned*>(h16 + (size_t)s0 * 128 + lane * 2);
    float a0 = a_s[(size_t)s0 * 8 + H] + adH + e0.x * MH0 + e0.y * MH1 + e0.z * MH2 + e0.w * MH3;
    a0 = a0 > 0.f ? a0 : NEG_SLOPE * a0;
    float p0 = __expf(a0);
    sum += p0;
    acc0 += p0 * __builtin_bit_cast(float, hu << 16);
    acc1 += p0 * __builtin_bit_cast(float, hu & 0xFFFF0000u);
  }
  float inv = 1.f / (sum + 1e-16f);
  float o0 = fmaxf(acc0 * inv + bias[lane * 2], 0.f);
  float o1 = fmaxf(acc1 * inv + bias[lane * 2 + 1], 0.f);
  *reinterpret_cast<float2*>(xout + (size_t)wid * 128 + lane * 2) = make_float2(o0, o1);
}

// ---------------- pooling + FC ----------------

#define PROWS 128
__global__ __launch_bounds__(128) void k_pool(const float* __restrict__ x,
    const int* __restrict__ batch, float* __restrict__ pool, int* __restrict__ cntg, int N) {
  int c = threadIdx.x;
  int n0 = blockIdx.x * PROWS;
  if (n0 >= N) return;
  int nend = min(n0 + PROWS, N);
  float acc = 0.f; int cnt = 0; int g = batch[n0];
  for (int n = n0; n < nend; ++n) {
    int bn = batch[n];
    if (bn != g) {
      atomicAdd(&pool[(size_t)g * 128 + c], acc);
      if (c == 0) atomicAdd(&cntg[g], cnt);
      acc = 0.f; cnt = 0; g = bn;
    }
    acc += x[(size_t)n * 128 + c];
    cnt++;
  }
  atomicAdd(&pool[(size_t)g * 128 + c], acc);
  if (c == 0) atomicAdd(&cntg[g], cnt);
}

__global__ __launch_bounds__(128) void k_fc(const float* __restrict__ pool,
    const int* __restrict__ cntg, const float* __restrict__ fcw,
    const float* __restrict__ fcb, float* __restrict__ out, int G) {
  int g = blockIdx.x, c = threadIdx.x;
  __shared__ float r0[2], r1[2];
  float inv = 1.f / (float)max(cntg[g], 1);
  float v = pool[(size_t)g * 128 + c] * inv;
  float p0 = v * fcw[c * 2], p1 = v * fcw[c * 2 + 1];
  for (int o = 1; o < 64; o <<= 1) { p0 += __shfl_xor(p0, o, 64); p1 += __shfl_xor(p1, o, 64); }
  if ((c & 63) == 0) { r0[c >> 6] = p0; r1[c >> 6] = p1; }
  __syncthreads();
  if (c == 0) {
    out[g * 2]     = r0[0] + r0[1] + fcb[0];
    out[g * 2 + 1] = r1[0] + r1[1] + fcb[1];
  }
}

// ---------------- host ----------------

extern "C" void kernel_launch(void* const* d_in, const int* in_sizes, int n_in,
                              void* d_out, int out_size, void* d_ws, size_t ws_size,
                              hipStream_t stream) {
  const float* x     = (const float*)d_in[0];
  const int*   eidx  = (const int*)d_in[1];
  const int*   batch = (const int*)d_in[2];
  const float* eattr = (const float*)d_in[3];
  const float* W1  = (const float*)d_in[4];
  const float* as1 = (const float*)d_in[5];
  const float* ad1 = (const float*)d_in[6];
  const float* We1 = (const float*)d_in[7];
  const float* ae1 = (const float*)d_in[8];
  const float* b1  = (const float*)d_in[9];
  const float* W2  = (const float*)d_in[10];
  const float* as2 = (const float*)d_in[11];
  const float* ad2 = (const float*)d_in[12];
  const float* We2 = (const float*)d_in[13];
  const float* ae2 = (const float*)d_in[14];
  const float* b2  = (const float*)d_in[15];
  const float* fcw = (const float*)d_in[16];
  const float* fcb = (const float*)d_in[17];

  const int N  = in_sizes[2];
  const int E  = in_sizes[1] / 2;
  const int G  = out_size / 2;
  const int E2 = E + N;
  const int nb = (N + 255) / 256;
  const int* srcI = eidx;
  const int* tgtI = eidx + E;

  char* w = (char*)d_ws;
  auto alloc = [&](size_t bytes) -> void* {
    void* p = (void*)w;
    w += (bytes + 255) & ~(size_t)255;
    return p;
  };
  int*   deg    = (int*)alloc((size_t)N * 8);        // deg + cur contiguous
  int*   cur    = deg + N;
  int*   bsum   = (int*)alloc((size_t)nb * 4);
  int*   off    = (int*)alloc((size_t)(N + 1) * 4);
  float* slot   = (float*)alloc((size_t)E2 * 32);
  float* a_s    = (float*)alloc((size_t)N * 32);
  float* a_d    = (float*)alloc((size_t)N * 32);
  unsigned short* x16 = (unsigned short*)alloc((size_t)N * 256);
  unsigned short* h16 = (unsigned short*)alloc((size_t)N * 256);
  unsigned short* W16t = (unsigned short*)alloc(128 * 128 * 2);
  float* xbuf   = (float*)alloc((size_t)N * 512);
  float* M      = (float*)alloc(512);                // M[64] + vab[64]
  float* vab    = M + 64;
  float* pool   = (float*)alloc((size_t)G * 512 + (size_t)G * 4);
  int*   cntg   = (int*)(pool + (size_t)G * 128);

  hipMemsetAsync(deg, 0, (size_t)N * 8, stream);
  hipMemsetAsync(pool, 0, (size_t)G * 516, stream);

  k_deg<<<(E + 255) / 256, 256, 0, stream>>>(tgtI, deg, E);
  k_bsum<<<nb, 256, 0, stream>>>(deg, bsum, N);
  k_bscan<<<1, 1024, 0, stream>>>(bsum, nb);
  k_off<<<nb, 256, 0, stream>>>(deg, bsum, off, slot, N);
  k_filledge<<<(E + 255) / 256, 256, 0, stream>>>(srcI, tgtI, eattr, off, cur, slot, E);
  k_loopattr<<<(N * 4 + 255) / 256, 256, 0, stream>>>(off, slot, N);
  k_M<<<1, 256, 0, stream>>>(We1, ae1, We2, ae2, W2, W1, as1, ad1, W16t, M, vab);

  // layer 1 (linearity: aggregate x then one matmul per node); output packed bf16
  k_node1<<<(N * 8 + 255) / 256, 256, 0, stream>>>(x, vab, a_s, a_d, N);
  k_aggr1<<<(N + 3) / 4, 256, 0, stream>>>(slot, off, a_s, a_d, M, x, W1, b1, x16, N);

  // layer 2 (MFMA linear + shuffle-alpha aggregate)
  k_node2<<<(N + 63) / 64, 256, 0, stream>>>(x16, W16t, as2, ad2, h16, a_s, a_d, N);
  k_aggr2<<<(N + 3) / 4, 256, 0, stream>>>(slot, off, a_s, a_d, M + 32, h16, b2, xbuf, N);

  // pool + fc
  k_pool<<<(N + PROWS - 1) / PROWS, 128, 0, stream>>>(xbuf, batch, pool, cntg, N);
  k_fc<<<G, 128, 0, stream>>>(pool, cntg, fcw, fcb, (float*)d_out, G);
}

// Round 8
// 262.684 us; speedup vs baseline: 3.4499x; 1.0793x over previous
//
#include <hip/hip_runtime.h>

#define NEG_SLOPE 0.2f

typedef __attribute__((ext_vector_type(8))) short bf16x8;
typedef __attribute__((ext_vector_type(4))) float f32x4;

__device__ __forceinline__ unsigned short f2bf(float f) {
  unsigned u = __builtin_bit_cast(unsigned, f);
  unsigned r = u + 0x7FFFu + ((u >> 16) & 1u);   // round-to-nearest-even
  return (unsigned short)(r >> 16);
}

// CSR slot: 32 B = {float ea[4]; int src; pad[3]}  (single-line scatter target)

// ---------------- graph preprocessing ----------------

__global__ void k_deg(const int* __restrict__ tgt, int* __restrict__ deg, int E) {
  int e = blockIdx.x * blockDim.x + threadIdx.x;
  if (e < E) atomicAdd(&deg[tgt[e]], 1);
}

// phase 1: per-block sums of (deg[i]+1) over 256-element chunks
__global__ __launch_bounds__(256) void k_bsum(const int* __restrict__ deg,
                                              int* __restrict__ bsum, int n) {
  __shared__ int ws[4];
  int i = blockIdx.x * 256 + threadIdx.x;
  int lane = threadIdx.x & 63, wv = threadIdx.x >> 6;
  int v = (i < n) ? deg[i] + 1 : 0;
  #pragma unroll
  for (int o = 1; o < 64; o <<= 1) v += __shfl_xor(v, o, 64);
  if (lane == 0) ws[wv] = v;
  __syncthreads();
  if (threadIdx.x == 0) bsum[blockIdx.x] = ws[0] + ws[1] + ws[2] + ws[3];
}

// phase 2: single block, exclusive scan of nb (<=1024) block sums
__global__ __launch_bounds__(1024) void k_bscan(int* __restrict__ bsum, int nb) {
  __shared__ int wsum[16];
  int tid = threadIdx.x, lane = tid & 63, wv = tid >> 6;
  int v = (tid < nb) ? bsum[tid] : 0;
  int sc = v;
  #pragma unroll
  for (int o = 1; o < 64; o <<= 1) { int t = __shfl_up(sc, o, 64); if (lane >= o) sc += t; }
  if (lane == 63) wsum[wv] = sc;
  __syncthreads();
  if (wv == 0 && lane < 16) {
    int ws = wsum[lane];
    #pragma unroll
    for (int o = 1; o < 16; o <<= 1) { int t = __shfl_up(ws, o, 64); if (lane >= o) ws += t; }
    wsum[lane] = ws;
  }
  __syncthreads();
  int excl = (wv ? wsum[wv - 1] : 0) + sc - v;
  if (tid < nb) bsum[tid] = excl;
}

// phase 3: per-block scan -> off[i+1]; self-loop src into last CSR slot
__global__ __launch_bounds__(256) void k_off(const int* __restrict__ deg,
                                             const int* __restrict__ bsum,
                                             int* __restrict__ off,
                                             float* __restrict__ slot, int n) {
  __shared__ int ws[4];
  int i = blockIdx.x * 256 + threadIdx.x;
  int lane = threadIdx.x & 63, wv = threadIdx.x >> 6;
  int v = (i < n) ? deg[i] + 1 : 0;
  int sc = v;
  #pragma unroll
  for (int o = 1; o < 64; o <<= 1) { int t = __shfl_up(sc, o, 64); if (lane >= o) sc += t; }
  if (lane == 63) ws[wv] = sc;
  __syncthreads();
  int pre = bsum[blockIdx.x];
  #pragma unroll
  for (int w = 0; w < 3; ++w) if (wv > w) pre += ws[w];
  int incl = pre + sc;
  if (i < n) {
    off[i + 1] = incl;
    reinterpret_cast<int*>(slot)[(size_t)(incl - 1) * 8 + 4] = i;  // self-loop src
  }
  if (i == 0) off[0] = 0;
}

// scatter edges into CSR slots: one aligned 32B chunk per edge
__global__ void k_filledge(const int* __restrict__ src, const int* __restrict__ tgt,
                           const float* __restrict__ eattr,
                           const int* __restrict__ off, int* __restrict__ cur,
                           float* __restrict__ slot, int E) {
  int e = blockIdx.x * blockDim.x + threadIdx.x;
  if (e >= E) return;
  int t = tgt[e];
  int pos = off[t] + atomicAdd(&cur[t], 1);
  reinterpret_cast<float4*>(slot)[(size_t)pos * 2] = reinterpret_cast<const float4*>(eattr)[e];
  reinterpret_cast<int*>(slot)[(size_t)pos * 8 + 4] = src[e];
}

// self-slot attr = mean of the node's incoming slot.ea rows (0 if none)
__global__ void k_loopattr(const int* __restrict__ off, float* __restrict__ slot, int N) {
  int idx = blockIdx.x * blockDim.x + threadIdx.x;
  int n = idx >> 2, c = idx & 3;
  if (n >= N) return;
  int beg = off[n], endS = off[n + 1] - 1;  // exclude self slot
  float s = 0.f;
  for (int i = beg; i < endS; ++i) s += slot[(size_t)i * 8 + c];
  slot[(size_t)endS * 8 + c] = s / (float)max(endS - beg, 1);
}

// M[layer][k][h]; W16t[c][k]=bf16(W2[k][c]); vab[kind][d][h]=sum_c W1[d][h*16+c]*att[h*16+c]
__global__ __launch_bounds__(256) void k_M(const float* __restrict__ We1, const float* __restrict__ ae1,
                    const float* __restrict__ We2, const float* __restrict__ ae2,
                    const float* __restrict__ W2, const float* __restrict__ W1,
                    const float* __restrict__ as1, const float* __restrict__ ad1,
                    unsigned short* __restrict__ W16t,
                    float* __restrict__ M, float* __restrict__ vab) {
  int tid = threadIdx.x;
  if (tid < 64) {
    int layer = tid >> 5, kh = tid & 31;
    int k = kh >> 3, h = kh & 7;
    const float* We = layer ? We2 : We1;
    const float* ae = layer ? ae2 : ae1;
    float acc = 0.f;
    for (int c = 0; c < 16; ++c) acc += We[k * 128 + h * 16 + c] * ae[h * 16 + c];
    M[layer * 32 + k * 8 + h] = acc;
  } else if (tid >= 128 && tid < 192) {
    int i = tid - 128;
    int kind = i >> 5, rem = i & 31;
    int d = rem >> 3, h = rem & 7;
    const float* att = kind ? ad1 : as1;
    float acc = 0.f;
    for (int c = 0; c < 16; ++c) acc += W1[d * 128 + h * 16 + c] * att[h * 16 + c];
    vab[kind * 32 + d * 8 + h] = acc;
  }
  for (int i = tid; i < 16384; i += 256) {
    int c = i >> 7, k = i & 127;
    W16t[c * 128 + k] = f2bf(W2[k * 128 + c]);
  }
}

// ---------------- layer kernels ----------------

// layer-1 node terms via low-rank tables: a_s[n][h] = x[n].va[:,h]
__global__ __launch_bounds__(256) void k_node1(const float* __restrict__ x,
    const float* __restrict__ vab, float* __restrict__ a_s, float* __restrict__ a_d, int N) {
  int idx = blockIdx.x * blockDim.x + threadIdx.x;
  int n = idx >> 3, h = idx & 7;
  if (n >= N) return;
  float4 xr = *reinterpret_cast<const float4*>(x + (size_t)n * 4);
  a_s[idx] = xr.x * vab[h] + xr.y * vab[8 + h] + xr.z * vab[16 + h] + xr.w * vab[24 + h];
  a_d[idx] = xr.x * vab[32 + h] + xr.y * vab[40 + h] + xr.z * vab[48 + h] + xr.w * vab[56 + h];
}

// layer-2 linear via MFMA: h2 = x16 @ W2 (bf16 in, f32 acc). One wave per 16-node tile.
__global__ __launch_bounds__(256) void k_node2(const unsigned short* __restrict__ x16,
    const unsigned short* __restrict__ W16t,
    const float* __restrict__ as_, const float* __restrict__ ad_,
    unsigned short* __restrict__ h16, float* __restrict__ a_s, float* __restrict__ a_d, int N) {
  int wv = threadIdx.x >> 6, lane = threadIdx.x & 63;
  int n0 = (blockIdx.x * 4 + wv) * 16;
  if (n0 >= N) return;
  int r = lane & 15, g = lane >> 4;
  bf16x8 a[4];
  #pragma unroll
  for (int kb = 0; kb < 4; ++kb)
    a[kb] = *reinterpret_cast<const bf16x8*>(x16 + (size_t)(n0 + r) * 128 + kb * 32 + g * 8);
  #pragma unroll
  for (int t = 0; t < 8; ++t) {
    f32x4 acc = {0.f, 0.f, 0.f, 0.f};
    #pragma unroll
    for (int kb = 0; kb < 4; ++kb) {
      bf16x8 b = *reinterpret_cast<const bf16x8*>(W16t + (size_t)(t * 16 + r) * 128 + kb * 32 + g * 8);
      acc = __builtin_amdgcn_mfma_f32_16x16x32_bf16(a[kb], b, acc, 0, 0, 0);
    }
    float asv = as_[t * 16 + r], adv = ad_[t * 16 + r];
    float ps[4], pd[4];
    #pragma unroll
    for (int j = 0; j < 4; ++j) { ps[j] = acc[j] * asv; pd[j] = acc[j] * adv; }
    #pragma unroll
    for (int o = 1; o < 16; o <<= 1) {
      #pragma unroll
      for (int j = 0; j < 4; ++j) {
        ps[j] += __shfl_xor(ps[j], o, 64);
        pd[j] += __shfl_xor(pd[j], o, 64);
      }
    }
    #pragma unroll
    for (int j = 0; j < 4; ++j) {
      int row = n0 + g * 4 + j;
      if (row < N) {
        h16[(size_t)row * 128 + t * 16 + r] = f2bf(acc[j]);
        if (r == 0) { a_s[(size_t)row * 8 + t] = ps[j]; a_d[(size_t)row * 8 + t] = pd[j]; }
      }
    }
  }
}

// layer-1 aggregate via LINEARITY: out = ((sum_e p_e x[src_e]) @ W1)/S + b.
// lane = (j<<3)|h : 8 edges in flight, one (edge,head) alpha per lane, X as float4.
__global__ __launch_bounds__(256) void k_aggr1(const float* __restrict__ slot,
    const int* __restrict__ off, const float* __restrict__ a_s, const float* __restrict__ a_d,
    const float* __restrict__ M, const float* __restrict__ x,
    const float* __restrict__ W, const float* __restrict__ bias,
    unsigned short* __restrict__ x16, int N) {
  int wid = (blockIdx.x * blockDim.x + threadIdx.x) >> 6;
  if (wid >= N) return;
  int lane = threadIdx.x & 63;
  int j = lane >> 3, h = lane & 7;
  float M0 = M[h], M1 = M[8 + h], M2 = M[16 + h], M3 = M[24 + h];
  float adv = a_d[(size_t)wid * 8 + h];
  int beg = off[wid], end = off[wid + 1];
  float S = 0.f, X0 = 0.f, X1 = 0.f, X2 = 0.f, X3 = 0.f;
  for (int i = beg; i < end; i += 8) {
    int ii = i + j;
    bool act = ii < end;
    int ib = act ? ii : end - 1;
    float4 ea = *reinterpret_cast<const float4*>(slot + (size_t)ib * 8);
    int s = reinterpret_cast<const int*>(slot)[(size_t)ib * 8 + 4];
    float asv = a_s[(size_t)s * 8 + h];
    float4 xv = *reinterpret_cast<const float4*>(x + (size_t)s * 4);
    float a = asv + adv + ea.x * M0 + ea.y * M1 + ea.z * M2 + ea.w * M3;
    a = a > 0.f ? a : NEG_SLOPE * a;
    float p = act ? __expf(a) : 0.f;
    S += p; X0 += p * xv.x; X1 += p * xv.y; X2 += p * xv.z; X3 += p * xv.w;
  }
  #pragma unroll
  for (int o = 8; o < 64; o <<= 1) {
    S  += __shfl_xor(S, o, 64);
    X0 += __shfl_xor(X0, o, 64); X1 += __shfl_xor(X1, o, 64);
    X2 += __shfl_xor(X2, o, 64); X3 += __shfl_xor(X3, o, 64);
  }
  int H = lane >> 3;       // consumer head for channels 2*lane, 2*lane+1
  float Sh = __shfl(S, H, 64);
  float y0 = __shfl(X0, H, 64), y1 = __shfl(X1, H, 64);
  float y2 = __shfl(X2, H, 64), y3 = __shfl(X3, H, 64);
  float inv = 1.f / (Sh + 1e-16f);
  int c0 = lane * 2, c1 = lane * 2 + 1;
  float o0 = (y0 * W[c0] + y1 * W[128 + c0] + y2 * W[256 + c0] + y3 * W[384 + c0]) * inv + bias[c0];
  float o1 = (y0 * W[c1] + y1 * W[128 + c1] + y2 * W[256 + c1] + y3 * W[384 + c1]) * inv + bias[c1];
  o0 = fmaxf(o0, 0.f); o1 = fmaxf(o1, 0.f);
  unsigned pk = ((unsigned)f2bf(o1) << 16) | (unsigned)f2bf(o0);
  *reinterpret_cast<unsigned*>(x16 + (size_t)wid * 128 + lane * 2) = pk;
}

// layer-2 aggregate: alpha computed once per (edge,head) on lane (j<<3)|h,
// broadcast via shuffles; per-lane bf16 h-row gather as before.
__global__ __launch_bounds__(256) void k_aggr2(const float* __restrict__ slot,
    const int* __restrict__ off, const float* __restrict__ a_s, const float* __restrict__ a_d,
    const float* __restrict__ M, const unsigned short* __restrict__ h16,
    const float* __restrict__ bias, float* __restrict__ xout, int N) {
  int wid = (blockIdx.x * blockDim.x + threadIdx.x) >> 6;
  if (wid >= N) return;
  int lane = threadIdx.x & 63;
  int H = lane >> 3;                   // consumer head
  int ja = lane >> 3, ha = lane & 7;   // alpha role: edge ja, head ha
  float Ma0 = M[ha], Ma1 = M[8 + ha], Ma2 = M[16 + ha], Ma3 = M[24 + ha];
  float MH0 = M[H],  MH1 = M[8 + H],  MH2 = M[16 + H],  MH3 = M[24 + H];
  float adA = a_d[(size_t)wid * 8 + ha];
  float adH = a_d[(size_t)wid * 8 + H];
  int beg = off[wid], end = off[wid + 1];
  float sum = 0.f, acc0 = 0.f, acc1 = 0.f;
  int i = beg;
  for (; i + 8 <= end; i += 8) {
    int ib = __builtin_amdgcn_readfirstlane(i);
    float4 ea = *reinterpret_cast<const float4*>(slot + (size_t)(ib + ja) * 8);
    int sA = reinterpret_cast<const int*>(slot)[(size_t)(ib + ja) * 8 + 4];
    float asv = a_s[(size_t)sA * 8 + ha];
    float a = asv + adA + ea.x * Ma0 + ea.y * Ma1 + ea.z * Ma2 + ea.w * Ma3;
    a = a > 0.f ? a : NEG_SLOPE * a;
    float p = __expf(a);
    #pragma unroll
    for (int jj = 0; jj < 8; ++jj) {
      int sj = __shfl(sA, jj * 8, 64);
      float pj = __shfl(p, jj * 8 + H, 64);
      unsigned hu = *reinterpret_cast<const unsigned*>(h16 + (size_t)sj * 128 + lane * 2);
      sum += pj;
      acc0 += pj * __builtin_bit_cast(float, hu << 16);
      acc1 += pj * __builtin_bit_cast(float, hu & 0xFFFF0000u);
    }
  }
  for (; i < end; ++i) {
    int ib = __builtin_amdgcn_readfirstlane(i);
    float4 e0 = *reinterpret_cast<const float4*>(slot + (size_t)ib * 8);
    int s0 = reinterpret_cast<const int*>(slot)[(size_t)ib * 8 + 4];
    unsigned hu = *reinterpret_cast<const unsigned*>(h16 + (size_t)s0 * 128 + lane * 2);
    float a0 = a_s[(size_t)s0 * 8 + H] + adH + e0.x * MH0 + e0.y * MH1 + e0.z * MH2 + e0.w * MH3;
    a0 = a0 > 0.f ? a0 : NEG_SLOPE * a0;
    float p0 = __expf(a0);
    sum += p0;
    acc0 += p0 * __builtin_bit_cast(float, hu << 16);
    acc1 += p0 * __builtin_bit_cast(float, hu & 0xFFFF0000u);
  }
  float inv = 1.f / (sum + 1e-16f);
  float o0 = fmaxf(acc0 * inv + bias[lane * 2], 0.f);
  float o1 = fmaxf(acc1 * inv + bias[lane * 2 + 1], 0.f);
  *reinterpret_cast<float2*>(xout + (size_t)wid * 128 + lane * 2) = make_float2(o0, o1);
}

// ---------------- pooling + FC ----------------

#define PROWS 128
__global__ __launch_bounds__(128) void k_pool(const float* __restrict__ x,
    const int* __restrict__ batch, float* __restrict__ pool, int* __restrict__ cntg, int N) {
  int c = threadIdx.x;
  int n0 = blockIdx.x * PROWS;
  if (n0 >= N) return;
  int nend = min(n0 + PROWS, N);
  float acc = 0.f; int cnt = 0; int g = batch[n0];
  for (int n = n0; n < nend; ++n) {
    int bn = batch[n];
    if (bn != g) {
      atomicAdd(&pool[(size_t)g * 128 + c], acc);
      if (c == 0) atomicAdd(&cntg[g], cnt);
      acc = 0.f; cnt = 0; g = bn;
    }
    acc += x[(size_t)n * 128 + c];
    cnt++;
  }
  atomicAdd(&pool[(size_t)g * 128 + c], acc);
  if (c == 0) atomicAdd(&cntg[g], cnt);
}

__global__ __launch_bounds__(128) void k_fc(const float* __restrict__ pool,
    const int* __restrict__ cntg, const float* __restrict__ fcw,
    const float* __restrict__ fcb, float* __restrict__ out, int G) {
  int g = blockIdx.x, c = threadIdx.x;
  __shared__ float r0[2], r1[2];
  float inv = 1.f / (float)max(cntg[g], 1);
  float v = pool[(size_t)g * 128 + c] * inv;
  float p0 = v * fcw[c * 2], p1 = v * fcw[c * 2 + 1];
  for (int o = 1; o < 64; o <<= 1) { p0 += __shfl_xor(p0, o, 64); p1 += __shfl_xor(p1, o, 64); }
  if ((c & 63) == 0) { r0[c >> 6] = p0; r1[c >> 6] = p1; }
  __syncthreads();
  if (c == 0) {
    out[g * 2]     = r0[0] + r0[1] + fcb[0];
    out[g * 2 + 1] = r1[0] + r1[1] + fcb[1];
  }
}

// ---------------- host ----------------

extern "C" void kernel_launch(void* const* d_in, const int* in_sizes, int n_in,
                              void* d_out, int out_size, void* d_ws, size_t ws_size,
                              hipStream_t stream) {
  const float* x     = (const float*)d_in[0];
  const int*   eidx  = (const int*)d_in[1];
  const int*   batch = (const int*)d_in[2];
  const float* eattr = (const float*)d_in[3];
  const float* W1  = (const float*)d_in[4];
  const float* as1 = (const float*)d_in[5];
  const float* ad1 = (const float*)d_in[6];
  const float* We1 = (const float*)d_in[7];
  const float* ae1 = (const float*)d_in[8];
  const float* b1  = (const float*)d_in[9];
  const float* W2  = (const float*)d_in[10];
  const float* as2 = (const float*)d_in[11];
  const float* ad2 = (const float*)d_in[12];
  const float* We2 = (const float*)d_in[13];
  const float* ae2 = (const float*)d_in[14];
  const float* b2  = (const float*)d_in[15];
  const float* fcw = (const float*)d_in[16];
  const float* fcb = (const float*)d_in[17];

  const int N  = in_sizes[2];
  const int E  = in_sizes[1] / 2;
  const int G  = out_size / 2;
  const int E2 = E + N;
  const int nb = (N + 255) / 256;
  const int* srcI = eidx;
  const int* tgtI = eidx + E;

  char* w = (char*)d_ws;
  auto alloc = [&](size_t bytes) -> void* {
    void* p = (void*)w;
    w += (bytes + 255) & ~(size_t)255;
    return p;
  };
  int*   deg    = (int*)alloc((size_t)N * 8);        // deg + cur contiguous
  int*   cur    = deg + N;
  int*   bsum   = (int*)alloc((size_t)nb * 4);
  int*   off    = (int*)alloc((size_t)(N + 1) * 4);
  float* slot   = (float*)alloc((size_t)E2 * 32);
  float* a_s    = (float*)alloc((size_t)N * 32);
  float* a_d    = (float*)alloc((size_t)N * 32);
  unsigned short* x16 = (unsigned short*)alloc((size_t)N * 256);
  unsigned short* h16 = (unsigned short*)alloc((size_t)N * 256);
  unsigned short* W16t = (unsigned short*)alloc(128 * 128 * 2);
  float* xbuf   = (float*)alloc((size_t)N * 512);
  float* M      = (float*)alloc(512);                // M[64] + vab[64]
  float* vab    = M + 64;
  float* pool   = (float*)alloc((size_t)G * 512 + (size_t)G * 4);
  int*   cntg   = (int*)(pool + (size_t)G * 128);

  hipMemsetAsync(deg, 0, (size_t)N * 8, stream);
  hipMemsetAsync(pool, 0, (size_t)G * 516, stream);

  k_deg<<<(E + 255) / 256, 256, 0, stream>>>(tgtI, deg, E);
  k_bsum<<<nb, 256, 0, stream>>>(deg, bsum, N);
  k_bscan<<<1, 1024, 0, stream>>>(bsum, nb);
  k_off<<<nb, 256, 0, stream>>>(deg, bsum, off, slot, N);
  k_filledge<<<(E + 255) / 256, 256, 0, stream>>>(srcI, tgtI, eattr, off, cur, slot, E);
  k_loopattr<<<(N * 4 + 255) / 256, 256, 0, stream>>>(off, slot, N);
  k_M<<<1, 256, 0, stream>>>(We1, ae1, We2, ae2, W2, W1, as1, ad1, W16t, M, vab);

  // layer 1 (linearity: aggregate x then one matmul per node); output packed bf16
  k_node1<<<(N * 8 + 255) / 256, 256, 0, stream>>>(x, vab, a_s, a_d, N);
  k_aggr1<<<(N + 3) / 4, 256, 0, stream>>>(slot, off, a_s, a_d, M, x, W1, b1, x16, N);

  // layer 2 (MFMA linear + shuffle-alpha aggregate)
  k_node2<<<(N + 63) / 64, 256, 0, stream>>>(x16, W16t, as2, ad2, h16, a_s, a_d, N);
  k_aggr2<<<(N + 3) / 4, 256, 0, stream>>>(slot, off, a_s, a_d, M + 32, h16, b2, xbuf, N);

  // pool + fc
  k_pool<<<(N + PROWS - 1) / PROWS, 128, 0, stream>>>(xbuf, batch, pool, cntg, N);
  k_fc<<<G, 128, 0, stream>>>(pool, cntg, fcw, fcb, (float*)d_out, G);
}